// Round 5
// baseline (4477.259 us; speedup 1.0000x reference)
//
#include <hip/hip_runtime.h>
#include <stdint.h>

#define NPTS 2048
#define NB 4
#define NROWS (NB * NPTS)
#define LNEG 0.2f

static __device__ __forceinline__ uint32_t sortable_f32(float f) {
  uint32_t u = __float_as_uint(f);
  return u ^ ((u >> 31) ? 0xFFFFFFFFu : 0x80000000u);
}

static __device__ __forceinline__ float lrelu(float t) { return t >= 0.f ? t : LNEG * t; }

// ---------------- local_idx dtype detect (bool u8 vs i32 vs i64) ----------------
__global__ void detect_mode_k(const uint32_t* __restrict__ loc, int* __restrict__ mode) {
  __shared__ uint32_t mAll, mOdd;
  if (threadIdx.x == 0) { mAll = 0u; mOdd = 0u; }
  __syncthreads();
  uint32_t a = 0u, o = 0u;
  for (int i = threadIdx.x; i < 2048; i += 256) {  // 8192 bytes: safe for every mode
    uint32_t v = loc[i];
    a = a > v ? a : v;
    if (i & 1) o = o > v ? o : v;
  }
  atomicMax(&mAll, a);
  atomicMax(&mOdd, o);
  __syncthreads();
  if (threadIdx.x == 0) {
    int m;
    if (mAll > 1u) m = 0;        // packed 1-byte bool
    else if (mOdd == 0u) m = 2;  // int64 (odd u32 words all zero)
    else m = 1;                  // int32
    *mode = m;
  }
}

__device__ __forceinline__ bool read_allow(const void* loc, int mode, int i) {
  if (mode == 0) return ((const uint8_t*)loc)[i] != 0;
  if (mode == 1) return ((const int*)loc)[i] != 0;
  return ((const uint32_t*)loc)[(size_t)i * 2] != 0;  // little-endian low word
}

// ---------------- prep: x transpose, weight transforms, BN fold ----------------
struct PrepArgs {
  const float* x; float* x0;
  const float* w[9]; float* wt[9];
  int O[9], C[9];
  const float* bn[11]; float* bns[11]; float* bnb[11];
  int bc[11];
};

__global__ void prep_k(PrepArgs pa) {
  int idx = blockIdx.x * 256 + threadIdx.x;
  if (idx < NROWS * 3) {               // x (B,3,N) -> x0 (B*N, 3)
    int c = idx % 3, r = idx / 3;
    int b = r >> 11, n = r & (NPTS - 1);
    pa.x0[idx] = pa.x[((size_t)b * 3 + c) * NPTS + n];
    return;
  }
  idx -= NROWS * 3;
  #pragma unroll
  for (int l = 0; l < 9; ++l) {
    int O = pa.O[l], C = pa.C[l];
    int n2 = (l == 8) ? O : 2 * O;
    int sz = C * n2;
    if (idx < sz) {
      int o = idx % n2, c = idx / n2;
      float v;
      if (l == 8) v = pa.w[l][(size_t)o * C + c];                     // plain transpose of w9
      else if (o < O) v = pa.w[l][(size_t)o * 2 * C + c];             // wA
      else v = pa.w[l][(size_t)(o - O) * 2 * C + C + c]
             - pa.w[l][(size_t)(o - O) * 2 * C + c];                  // wB - wA
      pa.wt[l][(size_t)c * n2 + o] = v;
      return;
    }
    idx -= sz;
  }
  #pragma unroll
  for (int i = 0; i < 11; ++i) {
    int C = pa.bc[i];
    if (idx < C) {
      float g = pa.bn[i][idx], b = pa.bn[i][C + idx];
      float m = pa.bn[i][2 * C + idx], v = pa.bn[i][3 * C + idx];
      float s = g * rsqrtf(v + 1e-5f);
      pa.bns[i][idx] = s;
      pa.bnb[i][idx] = b - m * s;
      return;
    }
    idx -= C;
  }
}

// ---------------- kNN: exact jax top_k replication (value desc, index asc) -----
__global__ __launch_bounds__(256) void knn_k(const float* __restrict__ geod,
                                             const void* __restrict__ loc,
                                             const int* __restrict__ modep,
                                             int* __restrict__ idxL,
                                             int* __restrict__ idxG) {
  int row = blockIdx.x;
  int b = row >> 11;
  int tid = threadIdx.x;
  int wid = tid >> 6, lane = tid & 63;
  int mode = *modep;
  const float* g = geod + (size_t)row * NPTS;

  float v[8]; bool al[8];
  float lmin = INFINITY;
  #pragma unroll
  for (int e = 0; e < 8; ++e) {
    int j = tid + 256 * e;
    v[e] = g[j];
    al[e] = read_allow(loc, mode, b * NPTS + j);
    lmin = fminf(lmin, v[e]);
  }
  __shared__ float sred[4];
  #pragma unroll
  for (int off = 32; off; off >>= 1) lmin = fminf(lmin, __shfl_xor(lmin, off));
  if (lane == 0) sred[wid] = lmin;
  __syncthreads();
  lmin = fminf(fminf(sred[0], sred[1]), fminf(sred[2], sred[3]));

  uint32_t smin = sortable_f32(lmin);
  unsigned long long keyL[8], keyG[8];
  #pragma unroll
  for (int e = 0; e < 8; ++e) {
    int j = tid + 256 * e;
    uint32_t sv = sortable_f32(v[e]);
    uint32_t kl = al[e] ? sv : smin;   // local conv: allowed = local_idx
    uint32_t kg = al[e] ? smin : sv;   // global conv: allowed = ~local_idx
    keyL[e] = ((unsigned long long)kl << 11) | (unsigned)(NPTS - 1 - j);
    keyG[e] = ((unsigned long long)kg << 11) | (unsigned)(NPTS - 1 - j);
  }

  // ping-pong shared slots: ONE barrier per extraction.
  __shared__ unsigned long long skey[2][4];
  auto runsel = [&](unsigned long long* key, int K, int* outp) {
    unsigned long long tmax = key[0];
    #pragma unroll
    for (int e = 1; e < 8; ++e) tmax = tmax > key[e] ? tmax : key[e];
    for (int it = 0; it < K; ++it) {
      unsigned long long m = tmax;
      #pragma unroll
      for (int off = 32; off; off >>= 1) {
        unsigned lo = __shfl_xor((unsigned)m, off);
        unsigned hi = __shfl_xor((unsigned)(m >> 32), off);
        unsigned long long om = ((unsigned long long)hi << 32) | lo;
        m = m > om ? m : om;
      }
      int s = it & 1;
      if (lane == 0) skey[s][wid] = m;
      __syncthreads();
      unsigned long long M = skey[s][0];
      #pragma unroll
      for (int w = 1; w < 4; ++w) M = M > skey[s][w] ? M : skey[s][w];
      int j = (NPTS - 1) - (int)(M & (unsigned long long)(NPTS - 1));
      if (tid == 0) outp[it] = j;
      if ((j & 255) == tid) {          // this thread owned the extracted key
        key[j >> 8] = 0ull;
        tmax = key[0];
        #pragma unroll
        for (int e = 1; e < 8; ++e) tmax = tmax > key[e] ? tmax : key[e];
      }
      // no trailing barrier: next write targets the other slot
    }
  };
  runsel(keyL, 16, idxL + (size_t)row * 16);
  runsel(keyG, 32, idxG + (size_t)row * 32);
}

// ---------------- fp32 tiled GEMM 64x64: C = A(MxK) * Bt(KxN2) ----------------
#define BM 64
#define BNC 64
#define BKC 16

__global__ __launch_bounds__(256) void gemm_k(const float* __restrict__ A, int lda,
                                              const float* __restrict__ Bt, int K, int N2,
                                              float* __restrict__ C, int ldc,
                                              const float* __restrict__ sc,
                                              const float* __restrict__ bi, int act) {
  __shared__ float As[BKC][BM + 4];   // row stride 272B = 16B-aligned
  __shared__ float Bs[BKC][BNC + 4];
  int tid = threadIdx.x;
  int tx = tid & 15, ty = tid >> 4;
  int m0 = blockIdx.x * BM, n0 = blockIdx.y * BNC;
  float acc[4][4] = {};
  for (int k0 = 0; k0 < K; k0 += BKC) {
    #pragma unroll
    for (int i = tid; i < BM * BKC; i += 256) {
      int kk = i & 15, mm = i >> 4;
      int kg = k0 + kk;
      As[kk][mm] = (kg < K) ? A[(size_t)(m0 + mm) * lda + kg] : 0.f;
    }
    #pragma unroll
    for (int i = tid; i < BKC * BNC; i += 256) {
      int nn = i & 63, kk = i >> 6;
      int kg = k0 + kk;
      Bs[kk][nn] = (kg < K) ? Bt[(size_t)kg * N2 + n0 + nn] : 0.f;
    }
    __syncthreads();
    #pragma unroll
    for (int k = 0; k < BKC; ++k) {
      float4 a4 = *(const float4*)&As[k][tx * 4];
      float4 b4 = *(const float4*)&Bs[k][ty * 4];
      float a[4] = {a4.x, a4.y, a4.z, a4.w};
      float bb[4] = {b4.x, b4.y, b4.z, b4.w};
      #pragma unroll
      for (int i2 = 0; i2 < 4; ++i2)
        #pragma unroll
        for (int j2 = 0; j2 < 4; ++j2)
          acc[i2][j2] = fmaf(a[i2], bb[j2], acc[i2][j2]);
    }
    __syncthreads();
  }
  #pragma unroll
  for (int i2 = 0; i2 < 4; ++i2) {
    int m = m0 + tx * 4 + i2;
    float4 o4;
    float* ov = (float*)&o4;
    #pragma unroll
    for (int j2 = 0; j2 < 4; ++j2) {
      int n = n0 + ty * 4 + j2;
      float vv = acc[i2][j2];
      if (act) {
        vv = fmaf(vv, sc[n], bi[n]);
        vv = lrelu(vv);
      }
      ov[j2] = vv;
    }
    *(float4*)&C[(size_t)m * ldc + n0 + ty * 4] = o4;
  }
}

// ------- big fp32 GEMM 128x128, double-buffered LDS, conflict-free 2x2x4x4 -----
#define GBM 128
#define GBN 128
#define GBK 16

__global__ __launch_bounds__(256, 4) void gemmbig_k(const float* __restrict__ A, int lda,
                                                    const float* __restrict__ Bt, int K, int N2,
                                                    float* __restrict__ C, int ldc,
                                                    const float* __restrict__ sc,
                                                    const float* __restrict__ bi, int act) {
  __shared__ float As[2][GBK][GBM + 4];
  __shared__ float Bs[2][GBK][GBN + 4];
  int tid = threadIdx.x;
  int tx = tid & 15, ty = tid >> 4;
  int m0 = blockIdx.x * GBM, n0 = blockIdx.y * GBN;
  // staging indices (K assumed multiple of 16 — true for 128/512)
  int ar = tid >> 2;            // 0..63
  int ak = (tid & 3) * 4;       // 0,4,8,12
  int bk = tid >> 4;            // 0..15
  int bc = (tid & 15) * 4;      // 0..60
  const int nk = K / GBK;
  float4 a0, a1, b0, b1;
  auto load_tile = [&](int kt) {
    int k0 = kt * GBK;
    a0 = *(const float4*)&A[(size_t)(m0 + ar) * lda + k0 + ak];
    a1 = *(const float4*)&A[(size_t)(m0 + 64 + ar) * lda + k0 + ak];
    b0 = *(const float4*)&Bt[(size_t)(k0 + bk) * N2 + n0 + bc];
    b1 = *(const float4*)&Bt[(size_t)(k0 + bk) * N2 + n0 + 64 + bc];
  };
  auto store_tile = [&](int buf) {
    As[buf][ak + 0][ar] = a0.x; As[buf][ak + 1][ar] = a0.y;
    As[buf][ak + 2][ar] = a0.z; As[buf][ak + 3][ar] = a0.w;
    As[buf][ak + 0][64 + ar] = a1.x; As[buf][ak + 1][64 + ar] = a1.y;
    As[buf][ak + 2][64 + ar] = a1.z; As[buf][ak + 3][64 + ar] = a1.w;
    *(float4*)&Bs[buf][bk][bc] = b0;
    *(float4*)&Bs[buf][bk][64 + bc] = b1;
  };
  float acc[2][2][4][4] = {};
  load_tile(0);
  store_tile(0);
  __syncthreads();
  for (int kt = 0; kt < nk; ++kt) {
    int cur = kt & 1;
    if (kt + 1 < nk) load_tile(kt + 1);
    #pragma unroll
    for (int k = 0; k < GBK; ++k) {
      float a[2][4], b[2][4];
      *(float4*)a[0] = *(const float4*)&As[cur][k][tx * 4];
      *(float4*)a[1] = *(const float4*)&As[cur][k][64 + tx * 4];
      *(float4*)b[0] = *(const float4*)&Bs[cur][k][ty * 4];
      *(float4*)b[1] = *(const float4*)&Bs[cur][k][64 + ty * 4];
      #pragma unroll
      for (int im = 0; im < 2; ++im)
        #pragma unroll
        for (int jn = 0; jn < 2; ++jn)
          #pragma unroll
          for (int i = 0; i < 4; ++i)
            #pragma unroll
            for (int j = 0; j < 4; ++j)
              acc[im][jn][i][j] = fmaf(a[im][i], b[jn][j], acc[im][jn][i][j]);
    }
    if (kt + 1 < nk) store_tile(1 - cur);
    __syncthreads();
  }
  #pragma unroll
  for (int im = 0; im < 2; ++im)
    #pragma unroll
    for (int i = 0; i < 4; ++i) {
      int m = m0 + im * 64 + tx * 4 + i;
      #pragma unroll
      for (int jn = 0; jn < 2; ++jn) {
        int nb = n0 + jn * 64 + ty * 4;
        float4 o4;
        float* ov = (float*)&o4;
        #pragma unroll
        for (int j = 0; j < 4; ++j) {
          float vv = acc[im][jn][i][j];
          if (act) {
            vv = fmaf(vv, sc[nb + j], bi[nb + j]);
            vv = lrelu(vv);
          }
          ov[j] = vv;
        }
        *(float4*)&C[(size_t)m * ldc + nb] = o4;
      }
    }
}

// ---------------- gather-max + BN + leaky: one wave per point ------------------
// vectorized per-lane channels: float4 for O>=256, float2 for O==128, scalar O==64
template<int K, int O>
__global__ __launch_bounds__(256) void gather_k(const float* __restrict__ z,
                                                const int* __restrict__ idx,
                                                const float* __restrict__ scale,
                                                const float* __restrict__ bias,
                                                float* __restrict__ outp) {
  constexpr int LDZ = 2 * O;
  int wid = threadIdx.x >> 6, lane = threadIdx.x & 63;
  int point = (blockIdx.x << 2) + wid;
  int b = point >> 11;
  const int* ip = idx + (size_t)point * K;
  int jj[K];
  #pragma unroll
  for (int k = 0; k < K; ++k) jj[k] = ip[k];
  if constexpr (O >= 256) {
    int c = lane * 4;                       // O==256: one float4 iter covers all
    float4 mx = {-INFINITY, -INFINITY, -INFINITY, -INFINITY};
    float4 mn = {INFINITY, INFINITY, INFINITY, INFINITY};
    #pragma unroll
    for (int k = 0; k < K; ++k) {
      float4 v = *(const float4*)&z[(size_t)((b << 11) + jj[k]) * LDZ + c];
      mx.x = fmaxf(mx.x, v.x); mx.y = fmaxf(mx.y, v.y);
      mx.z = fmaxf(mx.z, v.z); mx.w = fmaxf(mx.w, v.w);
      mn.x = fminf(mn.x, v.x); mn.y = fminf(mn.y, v.y);
      mn.z = fminf(mn.z, v.z); mn.w = fminf(mn.w, v.w);
    }
    float4 zc = *(const float4*)&z[(size_t)point * LDZ + O + c];
    float4 s = *(const float4*)&scale[c];
    float4 bb = *(const float4*)&bias[c];
    float4 o;
    o.x = lrelu(fmaf((s.x >= 0.f ? mx.x : mn.x) + zc.x, s.x, bb.x));
    o.y = lrelu(fmaf((s.y >= 0.f ? mx.y : mn.y) + zc.y, s.y, bb.y));
    o.z = lrelu(fmaf((s.z >= 0.f ? mx.z : mn.z) + zc.z, s.z, bb.z));
    o.w = lrelu(fmaf((s.w >= 0.f ? mx.w : mn.w) + zc.w, s.w, bb.w));
    *(float4*)&outp[(size_t)point * 512 + c] = o;
  } else if constexpr (O == 128) {
    int c = lane * 2;
    float2 mx = {-INFINITY, -INFINITY}, mn = {INFINITY, INFINITY};
    #pragma unroll
    for (int k = 0; k < K; ++k) {
      float2 v = *(const float2*)&z[(size_t)((b << 11) + jj[k]) * LDZ + c];
      mx.x = fmaxf(mx.x, v.x); mx.y = fmaxf(mx.y, v.y);
      mn.x = fminf(mn.x, v.x); mn.y = fminf(mn.y, v.y);
    }
    float2 zc = *(const float2*)&z[(size_t)point * LDZ + O + c];
    float2 s = *(const float2*)&scale[c];
    float2 bb = *(const float2*)&bias[c];
    float2 o;
    o.x = lrelu(fmaf((s.x >= 0.f ? mx.x : mn.x) + zc.x, s.x, bb.x));
    o.y = lrelu(fmaf((s.y >= 0.f ? mx.y : mn.y) + zc.y, s.y, bb.y));
    *(float2*)&outp[(size_t)point * 512 + c] = o;
  } else {
    int c = lane;
    float mx = -INFINITY, mn = INFINITY;
    #pragma unroll
    for (int k = 0; k < K; ++k) {
      float v = z[(size_t)((b << 11) + jj[k]) * LDZ + c];
      mx = fmaxf(mx, v);
      mn = fminf(mn, v);
    }
    float zc = z[(size_t)point * LDZ + O + c];
    float s = scale[c], bb = bias[c];
    float t = fmaf((s >= 0.f ? mx : mn) + zc, s, bb);
    outp[(size_t)point * 512 + c] = lrelu(t);
  }
}

// ---------------- xm = local_idx ? xcatL : xcatG ------------------------------
__global__ __launch_bounds__(256) void select_k(const float* __restrict__ xl,
                                                const float* __restrict__ xg,
                                                const void* __restrict__ loc,
                                                const int* __restrict__ modep,
                                                float* __restrict__ xm) {
  int i = blockIdx.x * 256 + threadIdx.x;   // over NROWS*128 float4
  int row = i >> 7;
  int mode = *modep;
  bool l = read_allow(loc, mode, row);
  const float4* s = (const float4*)(l ? xl : xg);
  ((float4*)xm)[i] = s[i];
}

// ---------------- per-(b,channel) max & mean over n ---------------------------
__global__ __launch_bounds__(256) void reduce_np_k(const float* __restrict__ y,
                                                   float* __restrict__ p) {
  int b = blockIdx.x >> 4, cb = blockIdx.x & 15;
  int wid = threadIdx.x >> 6, lane = threadIdx.x & 63;
  int c = cb * 64 + lane;
  float mx = -INFINITY, sm = 0.f;
  for (int n = wid; n < NPTS; n += 4) {
    float v = y[((size_t)(b * NPTS + n)) * 1024 + c];
    mx = fmaxf(mx, v);
    sm += v;
  }
  __shared__ float smx[4][64], ssm[4][64];
  smx[wid][lane] = mx;
  ssm[wid][lane] = sm;
  __syncthreads();
  if (wid == 0) {
    #pragma unroll
    for (int w = 1; w < 4; ++w) { mx = fmaxf(mx, smx[w][lane]); sm += ssm[w][lane]; }
    p[b * 2048 + c] = mx;
    p[b * 2048 + 1024 + c] = sm * (1.f / 2048.f);
  }
}

// ---------------- MLP layer kernels: one wave per output neuron ---------------
__global__ __launch_bounds__(256) void mlp1_k(const float* __restrict__ p,
                                              const float* __restrict__ w,
                                              const float* __restrict__ s10,
                                              const float* __restrict__ b10,
                                              float* __restrict__ h1) {
  int o = (blockIdx.x << 2) + (threadIdx.x >> 6);
  int lane = threadIdx.x & 63;
  const float4* wr = (const float4*)(w + (size_t)o * 2048);
  float acc[NB] = {};
  for (int i = lane; i < 512; i += 64) {
    float4 wv = wr[i];
    #pragma unroll
    for (int b = 0; b < NB; ++b) {
      float4 pv = ((const float4*)(p + b * 2048))[i];
      acc[b] += wv.x * pv.x + wv.y * pv.y + wv.z * pv.z + wv.w * pv.w;
    }
  }
  #pragma unroll
  for (int off = 32; off; off >>= 1)
    #pragma unroll
    for (int b = 0; b < NB; ++b) acc[b] += __shfl_xor(acc[b], off);
  if (lane == 0) {
    float sc = s10[o], bc = b10[o];
    #pragma unroll
    for (int b = 0; b < NB; ++b) h1[b * 512 + o] = lrelu(fmaf(acc[b], sc, bc));
  }
}

__global__ __launch_bounds__(256) void mlp2_k(const float* __restrict__ h1,
                                              const float* __restrict__ w,
                                              const float* __restrict__ l2b,
                                              const float* __restrict__ s11,
                                              const float* __restrict__ b11,
                                              float* __restrict__ h2) {
  int o = (blockIdx.x << 2) + (threadIdx.x >> 6);
  int lane = threadIdx.x & 63;
  const float4* wr = (const float4*)(w + (size_t)o * 512);
  float acc[NB] = {};
  for (int i = lane; i < 128; i += 64) {
    float4 wv = wr[i];
    #pragma unroll
    for (int b = 0; b < NB; ++b) {
      float4 pv = ((const float4*)(h1 + b * 512))[i];
      acc[b] += wv.x * pv.x + wv.y * pv.y + wv.z * pv.z + wv.w * pv.w;
    }
  }
  #pragma unroll
  for (int off = 32; off; off >>= 1)
    #pragma unroll
    for (int b = 0; b < NB; ++b) acc[b] += __shfl_xor(acc[b], off);
  if (lane == 0) {
    float bl = l2b[o], sc = s11[o], bc = b11[o];
    #pragma unroll
    for (int b = 0; b < NB; ++b) h2[b * 256 + o] = lrelu(fmaf(acc[b] + bl, sc, bc));
  }
}

__global__ __launch_bounds__(256) void mlp3_k(const float* __restrict__ h2,
                                              const float* __restrict__ w,
                                              const float* __restrict__ l3b,
                                              float* __restrict__ outp) {
  int o = (blockIdx.x << 2) + (threadIdx.x >> 6);
  int lane = threadIdx.x & 63;
  if (o >= 40) return;
  const float4* wr = (const float4*)(w + (size_t)o * 256);
  float acc[NB] = {};
  for (int i = lane; i < 64; i += 64) {
    float4 wv = wr[i];
    #pragma unroll
    for (int b = 0; b < NB; ++b) {
      float4 pv = ((const float4*)(h2 + b * 256))[i];
      acc[b] += wv.x * pv.x + wv.y * pv.y + wv.z * pv.z + wv.w * pv.w;
    }
  }
  #pragma unroll
  for (int off = 32; off; off >>= 1)
    #pragma unroll
    for (int b = 0; b < NB; ++b) acc[b] += __shfl_xor(acc[b], off);
  if (lane == 0) {
    float bl = l3b[o];
    #pragma unroll
    for (int b = 0; b < NB; ++b) outp[b * 40 + o] = acc[b] + bl;
  }
}

// ---------------- host orchestration ------------------------------------------
extern "C" void kernel_launch(void* const* d_in, const int* in_sizes, int n_in,
                              void* d_out, int out_size, void* d_ws, size_t ws_size,
                              hipStream_t stream) {
  const float* x = (const float*)d_in[0];
  const void* loc = d_in[1];
  const float* geod = (const float*)d_in[2];
  const float* w[9];
  for (int i = 0; i < 9; ++i) w[i] = (const float*)d_in[3 + i];
  const float* bn[11];
  for (int i = 0; i < 11; ++i) bn[i] = (const float*)d_in[12 + i];
  const float* l1w = (const float*)d_in[23];
  const float* l2w = (const float*)d_in[24];
  const float* l2b = (const float*)d_in[25];
  const float* l3w = (const float*)d_in[26];
  const float* l3b = (const float*)d_in[27];
  float* outp = (float*)d_out;

  char* base = (char*)d_ws;
  size_t off = 0;
  auto alloc = [&](size_t bytes) -> void* {
    void* p = base + off;
    off += (bytes + 255) & ~(size_t)255;
    return p;
  };
  int* mode = (int*)alloc(4);
  float* x0 = (float*)alloc((size_t)NROWS * 3 * 4);
  int* idxL = (int*)alloc((size_t)NROWS * 16 * 4);
  int* idxG = (int*)alloc((size_t)NROWS * 32 * 4);
  static const int Oc[9] = {64, 64, 128, 256, 64, 64, 128, 256, 1024};
  static const int Cc[9] = {3, 64, 64, 128, 3, 64, 64, 128, 512};
  float* wt[9];
  for (int l = 0; l < 9; ++l) {
    int n2 = (l == 8) ? Oc[l] : 2 * Oc[l];
    wt[l] = (float*)alloc((size_t)Cc[l] * n2 * 4);
  }
  static const int bc[11] = {64, 64, 128, 256, 64, 64, 128, 256, 1024, 512, 256};
  float *bns[11], *bnb[11];
  for (int i = 0; i < 11; ++i) {
    bns[i] = (float*)alloc((size_t)bc[i] * 4);
    bnb[i] = (float*)alloc((size_t)bc[i] * 4);
  }
  float* z = (float*)alloc((size_t)NROWS * 1024 * 4);      // reused: conv z / layer-9 y
  float* xcatL = (float*)alloc((size_t)NROWS * 512 * 4);
  float* xcatG = (float*)alloc((size_t)NROWS * 512 * 4);
  float* xm = (float*)alloc((size_t)NROWS * 512 * 4);
  float* pbuf = (float*)alloc((size_t)NB * 2048 * 4);
  float* h1 = (float*)alloc((size_t)NB * 512 * 4);
  float* h2 = (float*)alloc((size_t)NB * 256 * 4);

  detect_mode_k<<<1, 256, 0, stream>>>((const uint32_t*)loc, mode);

  PrepArgs pa;
  pa.x = x; pa.x0 = x0;
  for (int l = 0; l < 9; ++l) { pa.w[l] = w[l]; pa.wt[l] = wt[l]; pa.O[l] = Oc[l]; pa.C[l] = Cc[l]; }
  for (int i = 0; i < 11; ++i) { pa.bn[i] = bn[i]; pa.bns[i] = bns[i]; pa.bnb[i] = bnb[i]; pa.bc[i] = bc[i]; }
  int total = NROWS * 3;
  for (int l = 0; l < 9; ++l) total += Cc[l] * ((l == 8) ? Oc[l] : 2 * Oc[l]);
  for (int i = 0; i < 11; ++i) total += bc[i];
  prep_k<<<(total + 255) / 256, 256, 0, stream>>>(pa);

  knn_k<<<NROWS, 256, 0, stream>>>(geod, loc, mode, idxL, idxG);

  auto gemm = [&](const float* A, int lda, const float* Bt, int K, int N2, float* C, int ldc,
                  const float* sc, const float* bi, int act) {
    if (N2 >= 512) {
      dim3 grid(NROWS / GBM, N2 / GBN);
      gemmbig_k<<<grid, 256, 0, stream>>>(A, lda, Bt, K, N2, C, ldc, sc, bi, act);
    } else {
      dim3 grid(NROWS / BM, N2 / BNC);
      gemm_k<<<grid, 256, 0, stream>>>(A, lda, Bt, K, N2, C, ldc, sc, bi, act);
    }
  };
  auto gather = [&](int K, int O, const int* idx, const float* sc, const float* bi, float* op) {
    dim3 grid(NROWS / 4);
    if (K == 16) {
      if (O == 64)       gather_k<16, 64><<<grid, 256, 0, stream>>>(z, idx, sc, bi, op);
      else if (O == 128) gather_k<16, 128><<<grid, 256, 0, stream>>>(z, idx, sc, bi, op);
      else               gather_k<16, 256><<<grid, 256, 0, stream>>>(z, idx, sc, bi, op);
    } else {
      if (O == 64)       gather_k<32, 64><<<grid, 256, 0, stream>>>(z, idx, sc, bi, op);
      else if (O == 128) gather_k<32, 128><<<grid, 256, 0, stream>>>(z, idx, sc, bi, op);
      else               gather_k<32, 256><<<grid, 256, 0, stream>>>(z, idx, sc, bi, op);
    }
  };

  static const int coff[4] = {0, 64, 128, 256};
  for (int l = 0; l < 4; ++l) {   // local chain (K=16, w1-4, bn1-4)
    const float* A = (l == 0) ? x0 : (xcatL + coff[l - 1]);
    int lda = (l == 0) ? 3 : 512;
    gemm(A, lda, wt[l], Cc[l], 2 * Oc[l], z, 2 * Oc[l], nullptr, nullptr, 0);
    gather(16, Oc[l], idxL, bns[l], bnb[l], xcatL + coff[l]);
  }
  for (int l = 0; l < 4; ++l) {   // global chain (K=32, w5-8, bn5-8)
    const float* A = (l == 0) ? x0 : (xcatG + coff[l - 1]);
    int lda = (l == 0) ? 3 : 512;
    gemm(A, lda, wt[4 + l], Cc[4 + l], 2 * Oc[4 + l], z, 2 * Oc[4 + l], nullptr, nullptr, 0);
    gather(32, Oc[4 + l], idxG, bns[4 + l], bnb[4 + l], xcatG + coff[l]);
  }

  select_k<<<(NROWS * 512 / 4) / 256, 256, 0, stream>>>(xcatL, xcatG, loc, mode, xm);
  gemm(xm, 512, wt[8], 512, 1024, z, 1024, bns[8], bnb[8], 1);   // layer 9 + BN9 + leaky fused
  reduce_np_k<<<NB * 16, 256, 0, stream>>>(z, pbuf);
  mlp1_k<<<128, 256, 0, stream>>>(pbuf, l1w, bns[9], bnb[9], h1);
  mlp2_k<<<64, 256, 0, stream>>>(h1, l2w, l2b, bns[10], bnb[10], h2);
  mlp3_k<<<10, 256, 0, stream>>>(h2, l3w, l3b, outp);
}

// Round 6
// 946.715 us; speedup vs baseline: 4.7293x; 4.7293x over previous
//
#include <hip/hip_runtime.h>
#include <stdint.h>

#define NPTS 2048
#define NB 4
#define NROWS (NB * NPTS)
#define LNEG 0.2f

static __device__ __forceinline__ uint32_t sortable_f32(float f) {
  uint32_t u = __float_as_uint(f);
  return u ^ ((u >> 31) ? 0xFFFFFFFFu : 0x80000000u);
}

static __device__ __forceinline__ float lrelu(float t) { return t >= 0.f ? t : LNEG * t; }

// ---------------- local_idx dtype detect (bool u8 vs i32 vs i64) ----------------
__global__ void detect_mode_k(const uint32_t* __restrict__ loc, int* __restrict__ mode) {
  __shared__ uint32_t mAll, mOdd;
  if (threadIdx.x == 0) { mAll = 0u; mOdd = 0u; }
  __syncthreads();
  uint32_t a = 0u, o = 0u;
  for (int i = threadIdx.x; i < 2048; i += 256) {  // 8192 bytes: safe for every mode
    uint32_t v = loc[i];
    a = a > v ? a : v;
    if (i & 1) o = o > v ? o : v;
  }
  atomicMax(&mAll, a);
  atomicMax(&mOdd, o);
  __syncthreads();
  if (threadIdx.x == 0) {
    int m;
    if (mAll > 1u) m = 0;        // packed 1-byte bool
    else if (mOdd == 0u) m = 2;  // int64 (odd u32 words all zero)
    else m = 1;                  // int32
    *mode = m;
  }
}

__device__ __forceinline__ bool read_allow(const void* loc, int mode, int i) {
  if (mode == 0) return ((const uint8_t*)loc)[i] != 0;
  if (mode == 1) return ((const int*)loc)[i] != 0;
  return ((const uint32_t*)loc)[(size_t)i * 2] != 0;  // little-endian low word
}

// ---------------- prep: x transpose, weight transforms, BN fold ----------------
struct PrepArgs {
  const float* x; float* x0;
  const float* w[9]; float* wt[9];
  int O[9], C[9];
  const float* bn[11]; float* bns[11]; float* bnb[11];
  int bc[11];
};

__global__ void prep_k(PrepArgs pa) {
  int idx = blockIdx.x * 256 + threadIdx.x;
  if (idx < NROWS * 3) {               // x (B,3,N) -> x0 (B*N, 3)
    int c = idx % 3, r = idx / 3;
    int b = r >> 11, n = r & (NPTS - 1);
    pa.x0[idx] = pa.x[((size_t)b * 3 + c) * NPTS + n];
    return;
  }
  idx -= NROWS * 3;
  #pragma unroll
  for (int l = 0; l < 9; ++l) {
    int O = pa.O[l], C = pa.C[l];
    int n2 = (l == 8) ? O : 2 * O;
    int sz = C * n2;
    if (idx < sz) {
      int o = idx % n2, c = idx / n2;
      float v;
      if (l == 8) v = pa.w[l][(size_t)o * C + c];                     // plain transpose of w9
      else if (o < O) v = pa.w[l][(size_t)o * 2 * C + c];             // wA
      else v = pa.w[l][(size_t)(o - O) * 2 * C + C + c]
             - pa.w[l][(size_t)(o - O) * 2 * C + c];                  // wB - wA
      pa.wt[l][(size_t)c * n2 + o] = v;
      return;
    }
    idx -= sz;
  }
  #pragma unroll
  for (int i = 0; i < 11; ++i) {
    int C = pa.bc[i];
    if (idx < C) {
      float g = pa.bn[i][idx], b = pa.bn[i][C + idx];
      float m = pa.bn[i][2 * C + idx], v = pa.bn[i][3 * C + idx];
      float s = g * rsqrtf(v + 1e-5f);
      pa.bns[i][idx] = s;
      pa.bnb[i][idx] = b - m * s;
      return;
    }
    idx -= C;
  }
}

// ---------------- kNN: exact jax top_k replication (value desc, index asc) -----
__global__ __launch_bounds__(256) void knn_k(const float* __restrict__ geod,
                                             const void* __restrict__ loc,
                                             const int* __restrict__ modep,
                                             int* __restrict__ idxL,
                                             int* __restrict__ idxG) {
  int row = blockIdx.x;
  int b = row >> 11;
  int tid = threadIdx.x;
  int wid = tid >> 6, lane = tid & 63;
  int mode = *modep;
  const float* g = geod + (size_t)row * NPTS;

  float v[8]; bool al[8];
  float lmin = INFINITY;
  #pragma unroll
  for (int e = 0; e < 8; ++e) {
    int j = tid + 256 * e;
    v[e] = g[j];
    al[e] = read_allow(loc, mode, b * NPTS + j);
    lmin = fminf(lmin, v[e]);
  }
  __shared__ float sred[4];
  #pragma unroll
  for (int off = 32; off; off >>= 1) lmin = fminf(lmin, __shfl_xor(lmin, off));
  if (lane == 0) sred[wid] = lmin;
  __syncthreads();
  lmin = fminf(fminf(sred[0], sred[1]), fminf(sred[2], sred[3]));

  uint32_t smin = sortable_f32(lmin);
  unsigned long long keyL[8], keyG[8];
  #pragma unroll
  for (int e = 0; e < 8; ++e) {
    int j = tid + 256 * e;
    uint32_t sv = sortable_f32(v[e]);
    uint32_t kl = al[e] ? sv : smin;   // local conv: allowed = local_idx
    uint32_t kg = al[e] ? smin : sv;   // global conv: allowed = ~local_idx
    keyL[e] = ((unsigned long long)kl << 11) | (unsigned)(NPTS - 1 - j);
    keyG[e] = ((unsigned long long)kg << 11) | (unsigned)(NPTS - 1 - j);
  }

  // ping-pong shared slots: ONE barrier per extraction.
  __shared__ unsigned long long skey[2][4];
  auto runsel = [&](unsigned long long* key, int K, int* outp) {
    unsigned long long tmax = key[0];
    #pragma unroll
    for (int e = 1; e < 8; ++e) tmax = tmax > key[e] ? tmax : key[e];
    for (int it = 0; it < K; ++it) {
      unsigned long long m = tmax;
      #pragma unroll
      for (int off = 32; off; off >>= 1) {
        unsigned lo = __shfl_xor((unsigned)m, off);
        unsigned hi = __shfl_xor((unsigned)(m >> 32), off);
        unsigned long long om = ((unsigned long long)hi << 32) | lo;
        m = m > om ? m : om;
      }
      int s = it & 1;
      if (lane == 0) skey[s][wid] = m;
      __syncthreads();
      unsigned long long M = skey[s][0];
      #pragma unroll
      for (int w = 1; w < 4; ++w) M = M > skey[s][w] ? M : skey[s][w];
      int j = (NPTS - 1) - (int)(M & (unsigned long long)(NPTS - 1));
      if (tid == 0) outp[it] = j;
      if ((j & 255) == tid) {          // this thread owned the extracted key
        key[j >> 8] = 0ull;
        tmax = key[0];
        #pragma unroll
        for (int e = 1; e < 8; ++e) tmax = tmax > key[e] ? tmax : key[e];
      }
      // no trailing barrier: next write targets the other slot
    }
  };
  runsel(keyL, 16, idxL + (size_t)row * 16);
  runsel(keyG, 32, idxG + (size_t)row * 32);
}

// ---------------- fp32 tiled GEMM 64x64: C = A(MxK) * Bt(KxN2) ----------------
#define BM 64
#define BNC 64
#define BKC 16

__global__ __launch_bounds__(256) void gemm_k(const float* __restrict__ A, int lda,
                                              const float* __restrict__ Bt, int K, int N2,
                                              float* __restrict__ C, int ldc,
                                              const float* __restrict__ sc,
                                              const float* __restrict__ bi, int act) {
  __shared__ float As[BKC][BM + 4];   // row stride 272B = 16B-aligned
  __shared__ float Bs[BKC][BNC + 4];
  int tid = threadIdx.x;
  int tx = tid & 15, ty = tid >> 4;
  int m0 = blockIdx.x * BM, n0 = blockIdx.y * BNC;
  float acc[4][4] = {};
  for (int k0 = 0; k0 < K; k0 += BKC) {
    #pragma unroll
    for (int i = tid; i < BM * BKC; i += 256) {
      int kk = i & 15, mm = i >> 4;
      int kg = k0 + kk;
      As[kk][mm] = (kg < K) ? A[(size_t)(m0 + mm) * lda + kg] : 0.f;
    }
    #pragma unroll
    for (int i = tid; i < BKC * BNC; i += 256) {
      int nn = i & 63, kk = i >> 6;
      int kg = k0 + kk;
      Bs[kk][nn] = (kg < K) ? Bt[(size_t)kg * N2 + n0 + nn] : 0.f;
    }
    __syncthreads();
    #pragma unroll
    for (int k = 0; k < BKC; ++k) {
      float4 a4 = *(const float4*)&As[k][tx * 4];
      float4 b4 = *(const float4*)&Bs[k][ty * 4];
      float a[4] = {a4.x, a4.y, a4.z, a4.w};
      float bb[4] = {b4.x, b4.y, b4.z, b4.w};
      #pragma unroll
      for (int i2 = 0; i2 < 4; ++i2)
        #pragma unroll
        for (int j2 = 0; j2 < 4; ++j2)
          acc[i2][j2] = fmaf(a[i2], bb[j2], acc[i2][j2]);
    }
    __syncthreads();
  }
  #pragma unroll
  for (int i2 = 0; i2 < 4; ++i2) {
    int m = m0 + tx * 4 + i2;
    float4 o4;
    float* ov = (float*)&o4;
    #pragma unroll
    for (int j2 = 0; j2 < 4; ++j2) {
      int n = n0 + ty * 4 + j2;
      float vv = acc[i2][j2];
      if (act) {
        vv = fmaf(vv, sc[n], bi[n]);
        vv = lrelu(vv);
      }
      ov[j2] = vv;
    }
    *(float4*)&C[(size_t)m * ldc + n0 + ty * 4] = o4;
  }
}

// ------- big fp32 GEMM 128x128, double-buffered LDS, conflict-free 2x2x4x4 -----
// NOTE: no occupancy floor in __launch_bounds__! (256,4) clamped VGPRs to 64 and
// spilled all 64 accumulators -> 13 GB of scratch HBM traffic per dispatch (r5).
#define GBM 128
#define GBN 128
#define GBK 16

__global__ __launch_bounds__(256) void gemmbig_k(const float* __restrict__ A, int lda,
                                                 const float* __restrict__ Bt, int K, int N2,
                                                 float* __restrict__ C, int ldc,
                                                 const float* __restrict__ sc,
                                                 const float* __restrict__ bi, int act) {
  __shared__ float As[2][GBK][GBM + 4];
  __shared__ float Bs[2][GBK][GBN + 4];
  int tid = threadIdx.x;
  int tx = tid & 15, ty = tid >> 4;
  int m0 = blockIdx.x * GBM, n0 = blockIdx.y * GBN;
  // staging indices (K assumed multiple of 16 — true for 128/512)
  int ar = tid >> 2;            // 0..63
  int ak = (tid & 3) * 4;       // 0,4,8,12
  int bk = tid >> 4;            // 0..15
  int bc = (tid & 15) * 4;      // 0..60
  const int nk = K / GBK;
  float4 a0, a1, b0, b1;
  auto load_tile = [&](int kt) {
    int k0 = kt * GBK;
    a0 = *(const float4*)&A[(size_t)(m0 + ar) * lda + k0 + ak];
    a1 = *(const float4*)&A[(size_t)(m0 + 64 + ar) * lda + k0 + ak];
    b0 = *(const float4*)&Bt[(size_t)(k0 + bk) * N2 + n0 + bc];
    b1 = *(const float4*)&Bt[(size_t)(k0 + bk) * N2 + n0 + 64 + bc];
  };
  auto store_tile = [&](int buf) {
    As[buf][ak + 0][ar] = a0.x; As[buf][ak + 1][ar] = a0.y;
    As[buf][ak + 2][ar] = a0.z; As[buf][ak + 3][ar] = a0.w;
    As[buf][ak + 0][64 + ar] = a1.x; As[buf][ak + 1][64 + ar] = a1.y;
    As[buf][ak + 2][64 + ar] = a1.z; As[buf][ak + 3][64 + ar] = a1.w;
    *(float4*)&Bs[buf][bk][bc] = b0;
    *(float4*)&Bs[buf][bk][64 + bc] = b1;
  };
  float acc[2][2][4][4] = {};
  load_tile(0);
  store_tile(0);
  __syncthreads();
  for (int kt = 0; kt < nk; ++kt) {
    int cur = kt & 1;
    if (kt + 1 < nk) load_tile(kt + 1);
    #pragma unroll
    for (int k = 0; k < GBK; ++k) {
      float a[2][4], b[2][4];
      *(float4*)a[0] = *(const float4*)&As[cur][k][tx * 4];
      *(float4*)a[1] = *(const float4*)&As[cur][k][64 + tx * 4];
      *(float4*)b[0] = *(const float4*)&Bs[cur][k][ty * 4];
      *(float4*)b[1] = *(const float4*)&Bs[cur][k][64 + ty * 4];
      #pragma unroll
      for (int im = 0; im < 2; ++im)
        #pragma unroll
        for (int jn = 0; jn < 2; ++jn)
          #pragma unroll
          for (int i = 0; i < 4; ++i)
            #pragma unroll
            for (int j = 0; j < 4; ++j)
              acc[im][jn][i][j] = fmaf(a[im][i], b[jn][j], acc[im][jn][i][j]);
    }
    if (kt + 1 < nk) store_tile(1 - cur);
    __syncthreads();
  }
  #pragma unroll
  for (int im = 0; im < 2; ++im)
    #pragma unroll
    for (int i = 0; i < 4; ++i) {
      int m = m0 + im * 64 + tx * 4 + i;
      #pragma unroll
      for (int jn = 0; jn < 2; ++jn) {
        int nb = n0 + jn * 64 + ty * 4;
        float4 o4;
        float* ov = (float*)&o4;
        #pragma unroll
        for (int j = 0; j < 4; ++j) {
          float vv = acc[im][jn][i][j];
          if (act) {
            vv = fmaf(vv, sc[nb + j], bi[nb + j]);
            vv = lrelu(vv);
          }
          ov[j] = vv;
        }
        *(float4*)&C[(size_t)m * ldc + nb] = o4;
      }
    }
}

// ---------------- gather-max + BN + leaky: one wave per point ------------------
// vectorized per-lane channels: float4 for O>=256, float2 for O==128, scalar O==64
template<int K, int O>
__global__ __launch_bounds__(256) void gather_k(const float* __restrict__ z,
                                                const int* __restrict__ idx,
                                                const float* __restrict__ scale,
                                                const float* __restrict__ bias,
                                                float* __restrict__ outp) {
  constexpr int LDZ = 2 * O;
  int wid = threadIdx.x >> 6, lane = threadIdx.x & 63;
  int point = (blockIdx.x << 2) + wid;
  int b = point >> 11;
  const int* ip = idx + (size_t)point * K;
  int jj[K];
  #pragma unroll
  for (int k = 0; k < K; ++k) jj[k] = ip[k];
  if constexpr (O >= 256) {
    int c = lane * 4;                       // O==256: one float4 iter covers all
    float4 mx = {-INFINITY, -INFINITY, -INFINITY, -INFINITY};
    float4 mn = {INFINITY, INFINITY, INFINITY, INFINITY};
    #pragma unroll
    for (int k = 0; k < K; ++k) {
      float4 v = *(const float4*)&z[(size_t)((b << 11) + jj[k]) * LDZ + c];
      mx.x = fmaxf(mx.x, v.x); mx.y = fmaxf(mx.y, v.y);
      mx.z = fmaxf(mx.z, v.z); mx.w = fmaxf(mx.w, v.w);
      mn.x = fminf(mn.x, v.x); mn.y = fminf(mn.y, v.y);
      mn.z = fminf(mn.z, v.z); mn.w = fminf(mn.w, v.w);
    }
    float4 zc = *(const float4*)&z[(size_t)point * LDZ + O + c];
    float4 s = *(const float4*)&scale[c];
    float4 bb = *(const float4*)&bias[c];
    float4 o;
    o.x = lrelu(fmaf((s.x >= 0.f ? mx.x : mn.x) + zc.x, s.x, bb.x));
    o.y = lrelu(fmaf((s.y >= 0.f ? mx.y : mn.y) + zc.y, s.y, bb.y));
    o.z = lrelu(fmaf((s.z >= 0.f ? mx.z : mn.z) + zc.z, s.z, bb.z));
    o.w = lrelu(fmaf((s.w >= 0.f ? mx.w : mn.w) + zc.w, s.w, bb.w));
    *(float4*)&outp[(size_t)point * 512 + c] = o;
  } else if constexpr (O == 128) {
    int c = lane * 2;
    float2 mx = {-INFINITY, -INFINITY}, mn = {INFINITY, INFINITY};
    #pragma unroll
    for (int k = 0; k < K; ++k) {
      float2 v = *(const float2*)&z[(size_t)((b << 11) + jj[k]) * LDZ + c];
      mx.x = fmaxf(mx.x, v.x); mx.y = fmaxf(mx.y, v.y);
      mn.x = fminf(mn.x, v.x); mn.y = fminf(mn.y, v.y);
    }
    float2 zc = *(const float2*)&z[(size_t)point * LDZ + O + c];
    float2 s = *(const float2*)&scale[c];
    float2 bb = *(const float2*)&bias[c];
    float2 o;
    o.x = lrelu(fmaf((s.x >= 0.f ? mx.x : mn.x) + zc.x, s.x, bb.x));
    o.y = lrelu(fmaf((s.y >= 0.f ? mx.y : mn.y) + zc.y, s.y, bb.y));
    *(float2*)&outp[(size_t)point * 512 + c] = o;
  } else {
    int c = lane;
    float mx = -INFINITY, mn = INFINITY;
    #pragma unroll
    for (int k = 0; k < K; ++k) {
      float v = z[(size_t)((b << 11) + jj[k]) * LDZ + c];
      mx = fmaxf(mx, v);
      mn = fminf(mn, v);
    }
    float zc = z[(size_t)point * LDZ + O + c];
    float s = scale[c], bb = bias[c];
    float t = fmaf((s >= 0.f ? mx : mn) + zc, s, bb);
    outp[(size_t)point * 512 + c] = lrelu(t);
  }
}

// ---------------- xm = local_idx ? xcatL : xcatG ------------------------------
__global__ __launch_bounds__(256) void select_k(const float* __restrict__ xl,
                                                const float* __restrict__ xg,
                                                const void* __restrict__ loc,
                                                const int* __restrict__ modep,
                                                float* __restrict__ xm) {
  int i = blockIdx.x * 256 + threadIdx.x;   // over NROWS*128 float4
  int row = i >> 7;
  int mode = *modep;
  bool l = read_allow(loc, mode, row);
  const float4* s = (const float4*)(l ? xl : xg);
  ((float4*)xm)[i] = s[i];
}

// ---------------- per-(b,channel) max & mean over n ---------------------------
__global__ __launch_bounds__(256) void reduce_np_k(const float* __restrict__ y,
                                                   float* __restrict__ p) {
  int b = blockIdx.x >> 4, cb = blockIdx.x & 15;
  int wid = threadIdx.x >> 6, lane = threadIdx.x & 63;
  int c = cb * 64 + lane;
  float mx = -INFINITY, sm = 0.f;
  for (int n = wid; n < NPTS; n += 4) {
    float v = y[((size_t)(b * NPTS + n)) * 1024 + c];
    mx = fmaxf(mx, v);
    sm += v;
  }
  __shared__ float smx[4][64], ssm[4][64];
  smx[wid][lane] = mx;
  ssm[wid][lane] = sm;
  __syncthreads();
  if (wid == 0) {
    #pragma unroll
    for (int w = 1; w < 4; ++w) { mx = fmaxf(mx, smx[w][lane]); sm += ssm[w][lane]; }
    p[b * 2048 + c] = mx;
    p[b * 2048 + 1024 + c] = sm * (1.f / 2048.f);
  }
}

// ---------------- MLP layer kernels: one wave per output neuron ---------------
__global__ __launch_bounds__(256) void mlp1_k(const float* __restrict__ p,
                                              const float* __restrict__ w,
                                              const float* __restrict__ s10,
                                              const float* __restrict__ b10,
                                              float* __restrict__ h1) {
  int o = (blockIdx.x << 2) + (threadIdx.x >> 6);
  int lane = threadIdx.x & 63;
  const float4* wr = (const float4*)(w + (size_t)o * 2048);
  float acc[NB] = {};
  for (int i = lane; i < 512; i += 64) {
    float4 wv = wr[i];
    #pragma unroll
    for (int b = 0; b < NB; ++b) {
      float4 pv = ((const float4*)(p + b * 2048))[i];
      acc[b] += wv.x * pv.x + wv.y * pv.y + wv.z * pv.z + wv.w * pv.w;
    }
  }
  #pragma unroll
  for (int off = 32; off; off >>= 1)
    #pragma unroll
    for (int b = 0; b < NB; ++b) acc[b] += __shfl_xor(acc[b], off);
  if (lane == 0) {
    float sc = s10[o], bc = b10[o];
    #pragma unroll
    for (int b = 0; b < NB; ++b) h1[b * 512 + o] = lrelu(fmaf(acc[b], sc, bc));
  }
}

__global__ __launch_bounds__(256) void mlp2_k(const float* __restrict__ h1,
                                              const float* __restrict__ w,
                                              const float* __restrict__ l2b,
                                              const float* __restrict__ s11,
                                              const float* __restrict__ b11,
                                              float* __restrict__ h2) {
  int o = (blockIdx.x << 2) + (threadIdx.x >> 6);
  int lane = threadIdx.x & 63;
  const float4* wr = (const float4*)(w + (size_t)o * 512);
  float acc[NB] = {};
  for (int i = lane; i < 128; i += 64) {
    float4 wv = wr[i];
    #pragma unroll
    for (int b = 0; b < NB; ++b) {
      float4 pv = ((const float4*)(h1 + b * 512))[i];
      acc[b] += wv.x * pv.x + wv.y * pv.y + wv.z * pv.z + wv.w * pv.w;
    }
  }
  #pragma unroll
  for (int off = 32; off; off >>= 1)
    #pragma unroll
    for (int b = 0; b < NB; ++b) acc[b] += __shfl_xor(acc[b], off);
  if (lane == 0) {
    float bl = l2b[o], sc = s11[o], bc = b11[o];
    #pragma unroll
    for (int b = 0; b < NB; ++b) h2[b * 256 + o] = lrelu(fmaf(acc[b] + bl, sc, bc));
  }
}

__global__ __launch_bounds__(256) void mlp3_k(const float* __restrict__ h2,
                                              const float* __restrict__ w,
                                              const float* __restrict__ l3b,
                                              float* __restrict__ outp) {
  int o = (blockIdx.x << 2) + (threadIdx.x >> 6);
  int lane = threadIdx.x & 63;
  if (o >= 40) return;
  const float4* wr = (const float4*)(w + (size_t)o * 256);
  float acc[NB] = {};
  for (int i = lane; i < 64; i += 64) {
    float4 wv = wr[i];
    #pragma unroll
    for (int b = 0; b < NB; ++b) {
      float4 pv = ((const float4*)(h2 + b * 256))[i];
      acc[b] += wv.x * pv.x + wv.y * pv.y + wv.z * pv.z + wv.w * pv.w;
    }
  }
  #pragma unroll
  for (int off = 32; off; off >>= 1)
    #pragma unroll
    for (int b = 0; b < NB; ++b) acc[b] += __shfl_xor(acc[b], off);
  if (lane == 0) {
    float bl = l3b[o];
    #pragma unroll
    for (int b = 0; b < NB; ++b) outp[b * 40 + o] = acc[b] + bl;
  }
}

// ---------------- host orchestration ------------------------------------------
extern "C" void kernel_launch(void* const* d_in, const int* in_sizes, int n_in,
                              void* d_out, int out_size, void* d_ws, size_t ws_size,
                              hipStream_t stream) {
  const float* x = (const float*)d_in[0];
  const void* loc = d_in[1];
  const float* geod = (const float*)d_in[2];
  const float* w[9];
  for (int i = 0; i < 9; ++i) w[i] = (const float*)d_in[3 + i];
  const float* bn[11];
  for (int i = 0; i < 11; ++i) bn[i] = (const float*)d_in[12 + i];
  const float* l1w = (const float*)d_in[23];
  const float* l2w = (const float*)d_in[24];
  const float* l2b = (const float*)d_in[25];
  const float* l3w = (const float*)d_in[26];
  const float* l3b = (const float*)d_in[27];
  float* outp = (float*)d_out;

  char* base = (char*)d_ws;
  size_t off = 0;
  auto alloc = [&](size_t bytes) -> void* {
    void* p = base + off;
    off += (bytes + 255) & ~(size_t)255;
    return p;
  };
  int* mode = (int*)alloc(4);
  float* x0 = (float*)alloc((size_t)NROWS * 3 * 4);
  int* idxL = (int*)alloc((size_t)NROWS * 16 * 4);
  int* idxG = (int*)alloc((size_t)NROWS * 32 * 4);
  static const int Oc[9] = {64, 64, 128, 256, 64, 64, 128, 256, 1024};
  static const int Cc[9] = {3, 64, 64, 128, 3, 64, 64, 128, 512};
  float* wt[9];
  for (int l = 0; l < 9; ++l) {
    int n2 = (l == 8) ? Oc[l] : 2 * Oc[l];
    wt[l] = (float*)alloc((size_t)Cc[l] * n2 * 4);
  }
  static const int bc[11] = {64, 64, 128, 256, 64, 64, 128, 256, 1024, 512, 256};
  float *bns[11], *bnb[11];
  for (int i = 0; i < 11; ++i) {
    bns[i] = (float*)alloc((size_t)bc[i] * 4);
    bnb[i] = (float*)alloc((size_t)bc[i] * 4);
  }
  float* z = (float*)alloc((size_t)NROWS * 1024 * 4);      // reused: conv z / layer-9 y
  float* xcatL = (float*)alloc((size_t)NROWS * 512 * 4);
  float* xcatG = (float*)alloc((size_t)NROWS * 512 * 4);
  float* xm = (float*)alloc((size_t)NROWS * 512 * 4);
  float* pbuf = (float*)alloc((size_t)NB * 2048 * 4);
  float* h1 = (float*)alloc((size_t)NB * 512 * 4);
  float* h2 = (float*)alloc((size_t)NB * 256 * 4);

  detect_mode_k<<<1, 256, 0, stream>>>((const uint32_t*)loc, mode);

  PrepArgs pa;
  pa.x = x; pa.x0 = x0;
  for (int l = 0; l < 9; ++l) { pa.w[l] = w[l]; pa.wt[l] = wt[l]; pa.O[l] = Oc[l]; pa.C[l] = Cc[l]; }
  for (int i = 0; i < 11; ++i) { pa.bn[i] = bn[i]; pa.bns[i] = bns[i]; pa.bnb[i] = bnb[i]; pa.bc[i] = bc[i]; }
  int total = NROWS * 3;
  for (int l = 0; l < 9; ++l) total += Cc[l] * ((l == 8) ? Oc[l] : 2 * Oc[l]);
  for (int i = 0; i < 11; ++i) total += bc[i];
  prep_k<<<(total + 255) / 256, 256, 0, stream>>>(pa);

  knn_k<<<NROWS, 256, 0, stream>>>(geod, loc, mode, idxL, idxG);

  auto gemm = [&](const float* A, int lda, const float* Bt, int K, int N2, float* C, int ldc,
                  const float* sc, const float* bi, int act) {
    if (N2 >= 512) {
      dim3 grid(NROWS / GBM, N2 / GBN);
      gemmbig_k<<<grid, 256, 0, stream>>>(A, lda, Bt, K, N2, C, ldc, sc, bi, act);
    } else {
      dim3 grid(NROWS / BM, N2 / BNC);
      gemm_k<<<grid, 256, 0, stream>>>(A, lda, Bt, K, N2, C, ldc, sc, bi, act);
    }
  };
  auto gather = [&](int K, int O, const int* idx, const float* sc, const float* bi, float* op) {
    dim3 grid(NROWS / 4);
    if (K == 16) {
      if (O == 64)       gather_k<16, 64><<<grid, 256, 0, stream>>>(z, idx, sc, bi, op);
      else if (O == 128) gather_k<16, 128><<<grid, 256, 0, stream>>>(z, idx, sc, bi, op);
      else               gather_k<16, 256><<<grid, 256, 0, stream>>>(z, idx, sc, bi, op);
    } else {
      if (O == 64)       gather_k<32, 64><<<grid, 256, 0, stream>>>(z, idx, sc, bi, op);
      else if (O == 128) gather_k<32, 128><<<grid, 256, 0, stream>>>(z, idx, sc, bi, op);
      else               gather_k<32, 256><<<grid, 256, 0, stream>>>(z, idx, sc, bi, op);
    }
  };

  static const int coff[4] = {0, 64, 128, 256};
  for (int l = 0; l < 4; ++l) {   // local chain (K=16, w1-4, bn1-4)
    const float* A = (l == 0) ? x0 : (xcatL + coff[l - 1]);
    int lda = (l == 0) ? 3 : 512;
    gemm(A, lda, wt[l], Cc[l], 2 * Oc[l], z, 2 * Oc[l], nullptr, nullptr, 0);
    gather(16, Oc[l], idxL, bns[l], bnb[l], xcatL + coff[l]);
  }
  for (int l = 0; l < 4; ++l) {   // global chain (K=32, w5-8, bn5-8)
    const float* A = (l == 0) ? x0 : (xcatG + coff[l - 1]);
    int lda = (l == 0) ? 3 : 512;
    gemm(A, lda, wt[4 + l], Cc[4 + l], 2 * Oc[4 + l], z, 2 * Oc[4 + l], nullptr, nullptr, 0);
    gather(32, Oc[4 + l], idxG, bns[4 + l], bnb[4 + l], xcatG + coff[l]);
  }

  select_k<<<(NROWS * 512 / 4) / 256, 256, 0, stream>>>(xcatL, xcatG, loc, mode, xm);
  gemm(xm, 512, wt[8], 512, 1024, z, 1024, bns[8], bnb[8], 1);   // layer 9 + BN9 + leaky fused
  reduce_np_k<<<NB * 16, 256, 0, stream>>>(z, pbuf);
  mlp1_k<<<128, 256, 0, stream>>>(pbuf, l1w, bns[9], bnb[9], h1);
  mlp2_k<<<64, 256, 0, stream>>>(h1, l2w, l2b, bns[10], bnb[10], h2);
  mlp3_k<<<10, 256, 0, stream>>>(h2, l3w, l3b, outp);
}

// Round 7
// 891.433 us; speedup vs baseline: 5.0225x; 1.0620x over previous
//
#include <hip/hip_runtime.h>
#include <stdint.h>

#define NPTS 2048
#define NB 4
#define NROWS (NB * NPTS)
#define LNEG 0.2f

typedef unsigned long long u64;

static __device__ __forceinline__ uint32_t sortable_f32(float f) {
  uint32_t u = __float_as_uint(f);
  return u ^ ((u >> 31) ? 0xFFFFFFFFu : 0x80000000u);
}

static __device__ __forceinline__ float lrelu(float t) { return t >= 0.f ? t : LNEG * t; }

// ---------------- local_idx dtype detect (bool u8 vs i32 vs i64) ----------------
__global__ void detect_mode_k(const uint32_t* __restrict__ loc, int* __restrict__ mode) {
  __shared__ uint32_t mAll, mOdd;
  if (threadIdx.x == 0) { mAll = 0u; mOdd = 0u; }
  __syncthreads();
  uint32_t a = 0u, o = 0u;
  for (int i = threadIdx.x; i < 2048; i += 256) {  // 8192 bytes: safe for every mode
    uint32_t v = loc[i];
    a = a > v ? a : v;
    if (i & 1) o = o > v ? o : v;
  }
  atomicMax(&mAll, a);
  atomicMax(&mOdd, o);
  __syncthreads();
  if (threadIdx.x == 0) {
    int m;
    if (mAll > 1u) m = 0;        // packed 1-byte bool
    else if (mOdd == 0u) m = 2;  // int64 (odd u32 words all zero)
    else m = 1;                  // int32
    *mode = m;
  }
}

__device__ __forceinline__ bool read_allow(const void* loc, int mode, int i) {
  if (mode == 0) return ((const uint8_t*)loc)[i] != 0;
  if (mode == 1) return ((const int*)loc)[i] != 0;
  return ((const uint32_t*)loc)[(size_t)i * 2] != 0;  // little-endian low word
}

// ---------------- prep: x transpose, weight transforms, BN fold ----------------
struct PrepArgs {
  const float* x; float* x0;
  const float* w[9]; float* wt[9];
  int O[9], C[9];
  const float* bn[11]; float* bns[11]; float* bnb[11];
  int bc[11];
};

__global__ void prep_k(PrepArgs pa) {
  int idx = blockIdx.x * 256 + threadIdx.x;
  if (idx < NROWS * 3) {               // x (B,3,N) -> x0 (B*N, 3)
    int c = idx % 3, r = idx / 3;
    int b = r >> 11, n = r & (NPTS - 1);
    pa.x0[idx] = pa.x[((size_t)b * 3 + c) * NPTS + n];
    return;
  }
  idx -= NROWS * 3;
  #pragma unroll
  for (int l = 0; l < 9; ++l) {
    int O = pa.O[l], C = pa.C[l];
    int n2 = (l == 8) ? O : 2 * O;
    int sz = C * n2;
    if (idx < sz) {
      int o = idx % n2, c = idx / n2;
      float v;
      if (l == 8) v = pa.w[l][(size_t)o * C + c];                     // plain transpose of w9
      else if (o < O) v = pa.w[l][(size_t)o * 2 * C + c];             // wA
      else v = pa.w[l][(size_t)(o - O) * 2 * C + C + c]
             - pa.w[l][(size_t)(o - O) * 2 * C + c];                  // wB - wA
      pa.wt[l][(size_t)c * n2 + o] = v;
      return;
    }
    idx -= sz;
  }
  #pragma unroll
  for (int i = 0; i < 11; ++i) {
    int C = pa.bc[i];
    if (idx < C) {
      float g = pa.bn[i][idx], b = pa.bn[i][C + idx];
      float m = pa.bn[i][2 * C + idx], v = pa.bn[i][3 * C + idx];
      float s = g * rsqrtf(v + 1e-5f);
      pa.bns[i][idx] = s;
      pa.bnb[i][idx] = b - m * s;
      return;
    }
    idx -= C;
  }
}

// ---------------- kNN: exact jax top_k replication (value desc, index asc) -----
// All keys live in REGISTERS (static indexing only). Per extraction:
//  - every thread: 1 LDS u64 read (the one slot that changed) + 3 u64 compares
//  - owner wave only: 6-step u64 butterfly; owner thread: static-unrolled rescan
__global__ __launch_bounds__(256) void knn_k(const float* __restrict__ geod,
                                             const void* __restrict__ loc,
                                             const int* __restrict__ modep,
                                             int* __restrict__ idxL,
                                             int* __restrict__ idxG) {
  int row = blockIdx.x;
  int b = row >> 11;
  int tid = threadIdx.x;
  int wid = tid >> 6, lane = tid & 63;
  int mode = *modep;
  const float* g = geod + (size_t)row * NPTS;

  float v[8];
  uint32_t amask = 0;
  float lmin = INFINITY;
  #pragma unroll
  for (int e = 0; e < 8; ++e) {
    int j = tid + 256 * e;
    v[e] = g[j];
    if (read_allow(loc, mode, b * NPTS + j)) amask |= (1u << e);
    lmin = fminf(lmin, v[e]);
  }
  __shared__ float sred[4];
  #pragma unroll
  for (int off = 32; off; off >>= 1) lmin = fminf(lmin, __shfl_xor(lmin, off));
  if (lane == 0) sred[wid] = lmin;
  __syncthreads();
  lmin = fminf(fminf(sred[0], sred[1]), fminf(sred[2], sred[3]));
  uint32_t smin = sortable_f32(lmin);

  __shared__ u64 skey[2][4];

  // runsel: exact top-K extraction over the block's 2048 register-held keys
  auto runsel = [&](u64 (&key)[8], int K, int* outp) {
    u64 tmax = key[0];
    #pragma unroll
    for (int e = 1; e < 8; ++e) tmax = tmax > key[e] ? tmax : key[e];
    // init: every wave publishes its wave max into slot parity 0
    {
      u64 m = tmax;
      #pragma unroll
      for (int off = 32; off; off >>= 1) {
        unsigned lo = __shfl_xor((unsigned)m, off);
        unsigned hi = __shfl_xor((unsigned)(m >> 32), off);
        u64 om = ((u64)hi << 32) | lo;
        m = m > om ? m : om;
      }
      if (lane == 0) skey[0][wid] = m;
    }
    __syncthreads();
    u64 wm0 = skey[0][0], wm1 = skey[0][1], wm2 = skey[0][2], wm3 = skey[0][3];
    int wprev = 0;
    for (int it = 0; it < K; ++it) {
      if (it) {   // fold in the single slot updated last iteration
        u64 nv = skey[(it - 1) & 1][wprev];
        wm0 = (wprev == 0) ? nv : wm0;
        wm1 = (wprev == 1) ? nv : wm1;
        wm2 = (wprev == 2) ? nv : wm2;
        wm3 = (wprev == 3) ? nv : wm3;
      }
      u64 M = wm0; int ws = 0;
      if (wm1 > M) { M = wm1; ws = 1; }
      if (wm2 > M) { M = wm2; ws = 2; }
      if (wm3 > M) { M = wm3; ws = 3; }
      int j = (NPTS - 1) - (int)(M & (u64)(NPTS - 1));
      if (tid == 0) outp[it] = j;
      if (wid == ws) {                 // only the owning wave recomputes
        if ((j & 255) == tid) {        // owner thread: static-indexed update
          int e = j >> 8;
          #pragma unroll
          for (int t = 0; t < 8; ++t) key[t] = (t == e) ? 0ull : key[t];
          tmax = key[0];
          #pragma unroll
          for (int t = 1; t < 8; ++t) tmax = tmax > key[t] ? tmax : key[t];
        }
        u64 m = tmax;
        #pragma unroll
        for (int off = 32; off; off >>= 1) {
          unsigned lo = __shfl_xor((unsigned)m, off);
          unsigned hi = __shfl_xor((unsigned)(m >> 32), off);
          u64 om = ((u64)hi << 32) | lo;
          m = m > om ? m : om;
        }
        if (lane == 0) skey[it & 1][ws] = m;
      }
      wprev = ws;
      __syncthreads();
    }
  };

  {  // local chain keys (allowed = local_idx), K=16
    u64 keyL[8];
    #pragma unroll
    for (int e = 0; e < 8; ++e) {
      int j = tid + 256 * e;
      uint32_t sv = sortable_f32(v[e]);
      uint32_t kl = (amask >> e & 1u) ? sv : smin;
      keyL[e] = ((u64)kl << 11) | (unsigned)(NPTS - 1 - j);
    }
    runsel(keyL, 16, idxL + (size_t)row * 16);
  }
  {  // global chain keys (allowed = ~local_idx), K=32 — built AFTER L to cut pressure
    u64 keyG[8];
    #pragma unroll
    for (int e = 0; e < 8; ++e) {
      int j = tid + 256 * e;
      uint32_t sv = sortable_f32(v[e]);
      uint32_t kg = (amask >> e & 1u) ? smin : sv;
      keyG[e] = ((u64)kg << 11) | (unsigned)(NPTS - 1 - j);
    }
    runsel(keyG, 32, idxG + (size_t)row * 32);
  }
}

// ---------------- fp32 tiled GEMM 64x64: C = A(MxK) * Bt(KxN2) ----------------
#define BM 64
#define BNC 64
#define BKC 16

__global__ __launch_bounds__(256) void gemm_k(const float* __restrict__ A, int lda,
                                              const float* __restrict__ Bt, int K, int N2,
                                              float* __restrict__ C, int ldc,
                                              const float* __restrict__ sc,
                                              const float* __restrict__ bi, int act) {
  __shared__ float As[BKC][BM + 4];   // row stride 272B = 16B-aligned
  __shared__ float Bs[BKC][BNC + 4];
  int tid = threadIdx.x;
  int tx = tid & 15, ty = tid >> 4;
  int m0 = blockIdx.x * BM, n0 = blockIdx.y * BNC;
  float acc[4][4] = {};
  for (int k0 = 0; k0 < K; k0 += BKC) {
    #pragma unroll
    for (int i = tid; i < BM * BKC; i += 256) {
      int kk = i & 15, mm = i >> 4;
      int kg = k0 + kk;
      As[kk][mm] = (kg < K) ? A[(size_t)(m0 + mm) * lda + kg] : 0.f;
    }
    #pragma unroll
    for (int i = tid; i < BKC * BNC; i += 256) {
      int nn = i & 63, kk = i >> 6;
      int kg = k0 + kk;
      Bs[kk][nn] = (kg < K) ? Bt[(size_t)kg * N2 + n0 + nn] : 0.f;
    }
    __syncthreads();
    #pragma unroll
    for (int k = 0; k < BKC; ++k) {
      float4 a4 = *(const float4*)&As[k][tx * 4];
      float4 b4 = *(const float4*)&Bs[k][ty * 4];
      float a[4] = {a4.x, a4.y, a4.z, a4.w};
      float bb[4] = {b4.x, b4.y, b4.z, b4.w};
      #pragma unroll
      for (int i2 = 0; i2 < 4; ++i2)
        #pragma unroll
        for (int j2 = 0; j2 < 4; ++j2)
          acc[i2][j2] = fmaf(a[i2], bb[j2], acc[i2][j2]);
    }
    __syncthreads();
  }
  #pragma unroll
  for (int i2 = 0; i2 < 4; ++i2) {
    int m = m0 + tx * 4 + i2;
    float4 o4;
    float* ov = (float*)&o4;
    #pragma unroll
    for (int j2 = 0; j2 < 4; ++j2) {
      int n = n0 + ty * 4 + j2;
      float vv = acc[i2][j2];
      if (act) {
        vv = fmaf(vv, sc[n], bi[n]);
        vv = lrelu(vv);
      }
      ov[j2] = vv;
    }
    *(float4*)&C[(size_t)m * ldc + n0 + ty * 4] = o4;
  }
}

// ------- big fp32 GEMM 128x128, double-buffered LDS, conflict-free 2x2x4x4 -----
// NOTE: no occupancy floor in __launch_bounds__! (256,4) clamped VGPRs to 64 and
// spilled all 64 accumulators -> 13 GB of scratch HBM traffic per dispatch (r5).
#define GBM 128
#define GBN 128
#define GBK 16

__global__ __launch_bounds__(256) void gemmbig_k(const float* __restrict__ A, int lda,
                                                 const float* __restrict__ Bt, int K, int N2,
                                                 float* __restrict__ C, int ldc,
                                                 const float* __restrict__ sc,
                                                 const float* __restrict__ bi, int act) {
  __shared__ float As[2][GBK][GBM + 4];
  __shared__ float Bs[2][GBK][GBN + 4];
  int tid = threadIdx.x;
  int tx = tid & 15, ty = tid >> 4;
  int m0 = blockIdx.x * GBM, n0 = blockIdx.y * GBN;
  // staging indices (K assumed multiple of 16 — true for 128/512)
  int ar = tid >> 2;            // 0..63
  int ak = (tid & 3) * 4;       // 0,4,8,12
  int bk = tid >> 4;            // 0..15
  int bc = (tid & 15) * 4;      // 0..60
  const int nk = K / GBK;
  float4 a0, a1, b0, b1;
  auto load_tile = [&](int kt) {
    int k0 = kt * GBK;
    a0 = *(const float4*)&A[(size_t)(m0 + ar) * lda + k0 + ak];
    a1 = *(const float4*)&A[(size_t)(m0 + 64 + ar) * lda + k0 + ak];
    b0 = *(const float4*)&Bt[(size_t)(k0 + bk) * N2 + n0 + bc];
    b1 = *(const float4*)&Bt[(size_t)(k0 + bk) * N2 + n0 + 64 + bc];
  };
  auto store_tile = [&](int buf) {
    As[buf][ak + 0][ar] = a0.x; As[buf][ak + 1][ar] = a0.y;
    As[buf][ak + 2][ar] = a0.z; As[buf][ak + 3][ar] = a0.w;
    As[buf][ak + 0][64 + ar] = a1.x; As[buf][ak + 1][64 + ar] = a1.y;
    As[buf][ak + 2][64 + ar] = a1.z; As[buf][ak + 3][64 + ar] = a1.w;
    *(float4*)&Bs[buf][bk][bc] = b0;
    *(float4*)&Bs[buf][bk][64 + bc] = b1;
  };
  float acc[2][2][4][4] = {};
  load_tile(0);
  store_tile(0);
  __syncthreads();
  for (int kt = 0; kt < nk; ++kt) {
    int cur = kt & 1;
    if (kt + 1 < nk) load_tile(kt + 1);
    #pragma unroll
    for (int k = 0; k < GBK; ++k) {
      float a[2][4], b[2][4];
      *(float4*)a[0] = *(const float4*)&As[cur][k][tx * 4];
      *(float4*)a[1] = *(const float4*)&As[cur][k][64 + tx * 4];
      *(float4*)b[0] = *(const float4*)&Bs[cur][k][ty * 4];
      *(float4*)b[1] = *(const float4*)&Bs[cur][k][64 + ty * 4];
      #pragma unroll
      for (int im = 0; im < 2; ++im)
        #pragma unroll
        for (int jn = 0; jn < 2; ++jn)
          #pragma unroll
          for (int i = 0; i < 4; ++i)
            #pragma unroll
            for (int j = 0; j < 4; ++j)
              acc[im][jn][i][j] = fmaf(a[im][i], b[jn][j], acc[im][jn][i][j]);
    }
    if (kt + 1 < nk) store_tile(1 - cur);
    __syncthreads();
  }
  #pragma unroll
  for (int im = 0; im < 2; ++im)
    #pragma unroll
    for (int i = 0; i < 4; ++i) {
      int m = m0 + im * 64 + tx * 4 + i;
      #pragma unroll
      for (int jn = 0; jn < 2; ++jn) {
        int nb = n0 + jn * 64 + ty * 4;
        float4 o4;
        float* ov = (float*)&o4;
        #pragma unroll
        for (int j = 0; j < 4; ++j) {
          float vv = acc[im][jn][i][j];
          if (act) {
            vv = fmaf(vv, sc[nb + j], bi[nb + j]);
            vv = lrelu(vv);
          }
          ov[j] = vv;
        }
        *(float4*)&C[(size_t)m * ldc + nb] = o4;
      }
    }
}

// ---------------- gather-max + BN + leaky: one wave per point ------------------
// vectorized per-lane channels: float4 for O>=256, float2 for O==128, scalar O==64
template<int K, int O>
__global__ __launch_bounds__(256) void gather_k(const float* __restrict__ z,
                                                const int* __restrict__ idx,
                                                const float* __restrict__ scale,
                                                const float* __restrict__ bias,
                                                float* __restrict__ outp) {
  constexpr int LDZ = 2 * O;
  int wid = threadIdx.x >> 6, lane = threadIdx.x & 63;
  int point = (blockIdx.x << 2) + wid;
  int b = point >> 11;
  const int* ip = idx + (size_t)point * K;
  int jj[K];
  #pragma unroll
  for (int k = 0; k < K; ++k) jj[k] = ip[k];
  if constexpr (O >= 256) {
    int c = lane * 4;                       // O==256: one float4 iter covers all
    float4 mx = {-INFINITY, -INFINITY, -INFINITY, -INFINITY};
    float4 mn = {INFINITY, INFINITY, INFINITY, INFINITY};
    #pragma unroll
    for (int k = 0; k < K; ++k) {
      float4 v = *(const float4*)&z[(size_t)((b << 11) + jj[k]) * LDZ + c];
      mx.x = fmaxf(mx.x, v.x); mx.y = fmaxf(mx.y, v.y);
      mx.z = fmaxf(mx.z, v.z); mx.w = fmaxf(mx.w, v.w);
      mn.x = fminf(mn.x, v.x); mn.y = fminf(mn.y, v.y);
      mn.z = fminf(mn.z, v.z); mn.w = fminf(mn.w, v.w);
    }
    float4 zc = *(const float4*)&z[(size_t)point * LDZ + O + c];
    float4 s = *(const float4*)&scale[c];
    float4 bb = *(const float4*)&bias[c];
    float4 o;
    o.x = lrelu(fmaf((s.x >= 0.f ? mx.x : mn.x) + zc.x, s.x, bb.x));
    o.y = lrelu(fmaf((s.y >= 0.f ? mx.y : mn.y) + zc.y, s.y, bb.y));
    o.z = lrelu(fmaf((s.z >= 0.f ? mx.z : mn.z) + zc.z, s.z, bb.z));
    o.w = lrelu(fmaf((s.w >= 0.f ? mx.w : mn.w) + zc.w, s.w, bb.w));
    *(float4*)&outp[(size_t)point * 512 + c] = o;
  } else if constexpr (O == 128) {
    int c = lane * 2;
    float2 mx = {-INFINITY, -INFINITY}, mn = {INFINITY, INFINITY};
    #pragma unroll
    for (int k = 0; k < K; ++k) {
      float2 v = *(const float2*)&z[(size_t)((b << 11) + jj[k]) * LDZ + c];
      mx.x = fmaxf(mx.x, v.x); mx.y = fmaxf(mx.y, v.y);
      mn.x = fminf(mn.x, v.x); mn.y = fminf(mn.y, v.y);
    }
    float2 zc = *(const float2*)&z[(size_t)point * LDZ + O + c];
    float2 s = *(const float2*)&scale[c];
    float2 bb = *(const float2*)&bias[c];
    float2 o;
    o.x = lrelu(fmaf((s.x >= 0.f ? mx.x : mn.x) + zc.x, s.x, bb.x));
    o.y = lrelu(fmaf((s.y >= 0.f ? mx.y : mn.y) + zc.y, s.y, bb.y));
    *(float2*)&outp[(size_t)point * 512 + c] = o;
  } else {
    int c = lane;
    float mx = -INFINITY, mn = INFINITY;
    #pragma unroll
    for (int k = 0; k < K; ++k) {
      float v = z[(size_t)((b << 11) + jj[k]) * LDZ + c];
      mx = fmaxf(mx, v);
      mn = fminf(mn, v);
    }
    float zc = z[(size_t)point * LDZ + O + c];
    float s = scale[c], bb = bias[c];
    float t = fmaf((s >= 0.f ? mx : mn) + zc, s, bb);
    outp[(size_t)point * 512 + c] = lrelu(t);
  }
}

// ---------------- xm = local_idx ? xcatL : xcatG ------------------------------
__global__ __launch_bounds__(256) void select_k(const float* __restrict__ xl,
                                                const float* __restrict__ xg,
                                                const void* __restrict__ loc,
                                                const int* __restrict__ modep,
                                                float* __restrict__ xm) {
  int i = blockIdx.x * 256 + threadIdx.x;   // over NROWS*128 float4
  int row = i >> 7;
  int mode = *modep;
  bool l = read_allow(loc, mode, row);
  const float4* s = (const float4*)(l ? xl : xg);
  ((float4*)xm)[i] = s[i];
}

// ---------------- per-(b,channel) max & mean over n ---------------------------
__global__ __launch_bounds__(256) void reduce_np_k(const float* __restrict__ y,
                                                   float* __restrict__ p) {
  int b = blockIdx.x >> 4, cb = blockIdx.x & 15;
  int wid = threadIdx.x >> 6, lane = threadIdx.x & 63;
  int c = cb * 64 + lane;
  float mx = -INFINITY, sm = 0.f;
  for (int n = wid; n < NPTS; n += 4) {
    float v = y[((size_t)(b * NPTS + n)) * 1024 + c];
    mx = fmaxf(mx, v);
    sm += v;
  }
  __shared__ float smx[4][64], ssm[4][64];
  smx[wid][lane] = mx;
  ssm[wid][lane] = sm;
  __syncthreads();
  if (wid == 0) {
    #pragma unroll
    for (int w = 1; w < 4; ++w) { mx = fmaxf(mx, smx[w][lane]); sm += ssm[w][lane]; }
    p[b * 2048 + c] = mx;
    p[b * 2048 + 1024 + c] = sm * (1.f / 2048.f);
  }
}

// ---------------- MLP layer kernels: one wave per output neuron ---------------
__global__ __launch_bounds__(256) void mlp1_k(const float* __restrict__ p,
                                              const float* __restrict__ w,
                                              const float* __restrict__ s10,
                                              const float* __restrict__ b10,
                                              float* __restrict__ h1) {
  int o = (blockIdx.x << 2) + (threadIdx.x >> 6);
  int lane = threadIdx.x & 63;
  const float4* wr = (const float4*)(w + (size_t)o * 2048);
  float acc[NB] = {};
  for (int i = lane; i < 512; i += 64) {
    float4 wv = wr[i];
    #pragma unroll
    for (int b = 0; b < NB; ++b) {
      float4 pv = ((const float4*)(p + b * 2048))[i];
      acc[b] += wv.x * pv.x + wv.y * pv.y + wv.z * pv.z + wv.w * pv.w;
    }
  }
  #pragma unroll
  for (int off = 32; off; off >>= 1)
    #pragma unroll
    for (int b = 0; b < NB; ++b) acc[b] += __shfl_xor(acc[b], off);
  if (lane == 0) {
    float sc = s10[o], bc = b10[o];
    #pragma unroll
    for (int b = 0; b < NB; ++b) h1[b * 512 + o] = lrelu(fmaf(acc[b], sc, bc));
  }
}

__global__ __launch_bounds__(256) void mlp2_k(const float* __restrict__ h1,
                                              const float* __restrict__ w,
                                              const float* __restrict__ l2b,
                                              const float* __restrict__ s11,
                                              const float* __restrict__ b11,
                                              float* __restrict__ h2) {
  int o = (blockIdx.x << 2) + (threadIdx.x >> 6);
  int lane = threadIdx.x & 63;
  const float4* wr = (const float4*)(w + (size_t)o * 512);
  float acc[NB] = {};
  for (int i = lane; i < 128; i += 64) {
    float4 wv = wr[i];
    #pragma unroll
    for (int b = 0; b < NB; ++b) {
      float4 pv = ((const float4*)(h1 + b * 512))[i];
      acc[b] += wv.x * pv.x + wv.y * pv.y + wv.z * pv.z + wv.w * pv.w;
    }
  }
  #pragma unroll
  for (int off = 32; off; off >>= 1)
    #pragma unroll
    for (int b = 0; b < NB; ++b) acc[b] += __shfl_xor(acc[b], off);
  if (lane == 0) {
    float bl = l2b[o], sc = s11[o], bc = b11[o];
    #pragma unroll
    for (int b = 0; b < NB; ++b) h2[b * 256 + o] = lrelu(fmaf(acc[b] + bl, sc, bc));
  }
}

__global__ __launch_bounds__(256) void mlp3_k(const float* __restrict__ h2,
                                              const float* __restrict__ w,
                                              const float* __restrict__ l3b,
                                              float* __restrict__ outp) {
  int o = (blockIdx.x << 2) + (threadIdx.x >> 6);
  int lane = threadIdx.x & 63;
  if (o >= 40) return;
  const float4* wr = (const float4*)(w + (size_t)o * 256);
  float acc[NB] = {};
  for (int i = lane; i < 64; i += 64) {
    float4 wv = wr[i];
    #pragma unroll
    for (int b = 0; b < NB; ++b) {
      float4 pv = ((const float4*)(h2 + b * 256))[i];
      acc[b] += wv.x * pv.x + wv.y * pv.y + wv.z * pv.z + wv.w * pv.w;
    }
  }
  #pragma unroll
  for (int off = 32; off; off >>= 1)
    #pragma unroll
    for (int b = 0; b < NB; ++b) acc[b] += __shfl_xor(acc[b], off);
  if (lane == 0) {
    float bl = l3b[o];
    #pragma unroll
    for (int b = 0; b < NB; ++b) outp[b * 40 + o] = acc[b] + bl;
  }
}

// ---------------- host orchestration ------------------------------------------
extern "C" void kernel_launch(void* const* d_in, const int* in_sizes, int n_in,
                              void* d_out, int out_size, void* d_ws, size_t ws_size,
                              hipStream_t stream) {
  const float* x = (const float*)d_in[0];
  const void* loc = d_in[1];
  const float* geod = (const float*)d_in[2];
  const float* w[9];
  for (int i = 0; i < 9; ++i) w[i] = (const float*)d_in[3 + i];
  const float* bn[11];
  for (int i = 0; i < 11; ++i) bn[i] = (const float*)d_in[12 + i];
  const float* l1w = (const float*)d_in[23];
  const float* l2w = (const float*)d_in[24];
  const float* l2b = (const float*)d_in[25];
  const float* l3w = (const float*)d_in[26];
  const float* l3b = (const float*)d_in[27];
  float* outp = (float*)d_out;

  char* base = (char*)d_ws;
  size_t off = 0;
  auto alloc = [&](size_t bytes) -> void* {
    void* p = base + off;
    off += (bytes + 255) & ~(size_t)255;
    return p;
  };
  int* mode = (int*)alloc(4);
  float* x0 = (float*)alloc((size_t)NROWS * 3 * 4);
  int* idxL = (int*)alloc((size_t)NROWS * 16 * 4);
  int* idxG = (int*)alloc((size_t)NROWS * 32 * 4);
  static const int Oc[9] = {64, 64, 128, 256, 64, 64, 128, 256, 1024};
  static const int Cc[9] = {3, 64, 64, 128, 3, 64, 64, 128, 512};
  float* wt[9];
  for (int l = 0; l < 9; ++l) {
    int n2 = (l == 8) ? Oc[l] : 2 * Oc[l];
    wt[l] = (float*)alloc((size_t)Cc[l] * n2 * 4);
  }
  static const int bc[11] = {64, 64, 128, 256, 64, 64, 128, 256, 1024, 512, 256};
  float *bns[11], *bnb[11];
  for (int i = 0; i < 11; ++i) {
    bns[i] = (float*)alloc((size_t)bc[i] * 4);
    bnb[i] = (float*)alloc((size_t)bc[i] * 4);
  }
  float* z = (float*)alloc((size_t)NROWS * 1024 * 4);      // reused: conv z / layer-9 y
  float* xcatL = (float*)alloc((size_t)NROWS * 512 * 4);
  float* xcatG = (float*)alloc((size_t)NROWS * 512 * 4);
  float* xm = (float*)alloc((size_t)NROWS * 512 * 4);
  float* pbuf = (float*)alloc((size_t)NB * 2048 * 4);
  float* h1 = (float*)alloc((size_t)NB * 512 * 4);
  float* h2 = (float*)alloc((size_t)NB * 256 * 4);

  detect_mode_k<<<1, 256, 0, stream>>>((const uint32_t*)loc, mode);

  PrepArgs pa;
  pa.x = x; pa.x0 = x0;
  for (int l = 0; l < 9; ++l) { pa.w[l] = w[l]; pa.wt[l] = wt[l]; pa.O[l] = Oc[l]; pa.C[l] = Cc[l]; }
  for (int i = 0; i < 11; ++i) { pa.bn[i] = bn[i]; pa.bns[i] = bns[i]; pa.bnb[i] = bnb[i]; pa.bc[i] = bc[i]; }
  int total = NROWS * 3;
  for (int l = 0; l < 9; ++l) total += Cc[l] * ((l == 8) ? Oc[l] : 2 * Oc[l]);
  for (int i = 0; i < 11; ++i) total += bc[i];
  prep_k<<<(total + 255) / 256, 256, 0, stream>>>(pa);

  knn_k<<<NROWS, 256, 0, stream>>>(geod, loc, mode, idxL, idxG);

  auto gemm = [&](const float* A, int lda, const float* Bt, int K, int N2, float* C, int ldc,
                  const float* sc, const float* bi, int act) {
    if (N2 >= 512) {
      dim3 grid(NROWS / GBM, N2 / GBN);
      gemmbig_k<<<grid, 256, 0, stream>>>(A, lda, Bt, K, N2, C, ldc, sc, bi, act);
    } else {
      dim3 grid(NROWS / BM, N2 / BNC);
      gemm_k<<<grid, 256, 0, stream>>>(A, lda, Bt, K, N2, C, ldc, sc, bi, act);
    }
  };
  auto gather = [&](int K, int O, const int* idx, const float* sc, const float* bi, float* op) {
    dim3 grid(NROWS / 4);
    if (K == 16) {
      if (O == 64)       gather_k<16, 64><<<grid, 256, 0, stream>>>(z, idx, sc, bi, op);
      else if (O == 128) gather_k<16, 128><<<grid, 256, 0, stream>>>(z, idx, sc, bi, op);
      else               gather_k<16, 256><<<grid, 256, 0, stream>>>(z, idx, sc, bi, op);
    } else {
      if (O == 64)       gather_k<32, 64><<<grid, 256, 0, stream>>>(z, idx, sc, bi, op);
      else if (O == 128) gather_k<32, 128><<<grid, 256, 0, stream>>>(z, idx, sc, bi, op);
      else               gather_k<32, 256><<<grid, 256, 0, stream>>>(z, idx, sc, bi, op);
    }
  };

  static const int coff[4] = {0, 64, 128, 256};
  for (int l = 0; l < 4; ++l) {   // local chain (K=16, w1-4, bn1-4)
    const float* A = (l == 0) ? x0 : (xcatL + coff[l - 1]);
    int lda = (l == 0) ? 3 : 512;
    gemm(A, lda, wt[l], Cc[l], 2 * Oc[l], z, 2 * Oc[l], nullptr, nullptr, 0);
    gather(16, Oc[l], idxL, bns[l], bnb[l], xcatL + coff[l]);
  }
  for (int l = 0; l < 4; ++l) {   // global chain (K=32, w5-8, bn5-8)
    const float* A = (l == 0) ? x0 : (xcatG + coff[l - 1]);
    int lda = (l == 0) ? 3 : 512;
    gemm(A, lda, wt[4 + l], Cc[4 + l], 2 * Oc[4 + l], z, 2 * Oc[4 + l], nullptr, nullptr, 0);
    gather(32, Oc[4 + l], idxG, bns[4 + l], bnb[4 + l], xcatG + coff[l]);
  }

  select_k<<<(NROWS * 512 / 4) / 256, 256, 0, stream>>>(xcatL, xcatG, loc, mode, xm);
  gemm(xm, 512, wt[8], 512, 1024, z, 1024, bns[8], bnb[8], 1);   // layer 9 + BN9 + leaky fused
  reduce_np_k<<<NB * 16, 256, 0, stream>>>(z, pbuf);
  mlp1_k<<<128, 256, 0, stream>>>(pbuf, l1w, bns[9], bnb[9], h1);
  mlp2_k<<<64, 256, 0, stream>>>(h1, l2w, l2b, bns[10], bnb[10], h2);
  mlp3_k<<<10, 256, 0, stream>>>(h2, l3w, l3b, outp);
}

// Round 8
// 858.991 us; speedup vs baseline: 5.2122x; 1.0378x over previous
//
#include <hip/hip_runtime.h>
#include <stdint.h>

#define NPTS 2048
#define NB 4
#define NROWS (NB * NPTS)
#define LNEG 0.2f

typedef unsigned long long u64;

static __device__ __forceinline__ uint32_t sortable_f32(float f) {
  uint32_t u = __float_as_uint(f);
  return u ^ ((u >> 31) ? 0xFFFFFFFFu : 0x80000000u);
}

static __device__ __forceinline__ float lrelu(float t) { return t >= 0.f ? t : LNEG * t; }

// ---------------- local_idx dtype detect (bool u8 vs i32 vs i64) ----------------
__global__ void detect_mode_k(const uint32_t* __restrict__ loc, int* __restrict__ mode) {
  __shared__ uint32_t mAll, mOdd;
  if (threadIdx.x == 0) { mAll = 0u; mOdd = 0u; }
  __syncthreads();
  uint32_t a = 0u, o = 0u;
  for (int i = threadIdx.x; i < 2048; i += 256) {  // 8192 bytes: safe for every mode
    uint32_t v = loc[i];
    a = a > v ? a : v;
    if (i & 1) o = o > v ? o : v;
  }
  atomicMax(&mAll, a);
  atomicMax(&mOdd, o);
  __syncthreads();
  if (threadIdx.x == 0) {
    int m;
    if (mAll > 1u) m = 0;        // packed 1-byte bool
    else if (mOdd == 0u) m = 2;  // int64 (odd u32 words all zero)
    else m = 1;                  // int32
    *mode = m;
  }
}

__device__ __forceinline__ bool read_allow(const void* loc, int mode, int i) {
  if (mode == 0) return ((const uint8_t*)loc)[i] != 0;
  if (mode == 1) return ((const int*)loc)[i] != 0;
  return ((const uint32_t*)loc)[(size_t)i * 2] != 0;  // little-endian low word
}

// ---------------- prep: x transpose, weight transforms, BN fold ----------------
struct PrepArgs {
  const float* x; float* x0;
  const float* w[9]; float* wt[9];
  int O[9], C[9];
  const float* bn[11]; float* bns[11]; float* bnb[11];
  int bc[11];
};

__global__ void prep_k(PrepArgs pa) {
  int idx = blockIdx.x * 256 + threadIdx.x;
  if (idx < NROWS * 3) {               // x (B,3,N) -> x0 (B*N, 3)
    int c = idx % 3, r = idx / 3;
    int b = r >> 11, n = r & (NPTS - 1);
    pa.x0[idx] = pa.x[((size_t)b * 3 + c) * NPTS + n];
    return;
  }
  idx -= NROWS * 3;
  #pragma unroll
  for (int l = 0; l < 9; ++l) {
    int O = pa.O[l], C = pa.C[l];
    int n2 = (l == 8) ? O : 2 * O;
    int sz = C * n2;
    if (idx < sz) {
      int o = idx % n2, c = idx / n2;
      float v;
      if (l == 8) v = pa.w[l][(size_t)o * C + c];                     // plain transpose of w9
      else if (o < O) v = pa.w[l][(size_t)o * 2 * C + c];             // wA
      else v = pa.w[l][(size_t)(o - O) * 2 * C + C + c]
             - pa.w[l][(size_t)(o - O) * 2 * C + c];                  // wB - wA
      pa.wt[l][(size_t)c * n2 + o] = v;
      return;
    }
    idx -= sz;
  }
  #pragma unroll
  for (int i = 0; i < 11; ++i) {
    int C = pa.bc[i];
    if (idx < C) {
      float g = pa.bn[i][idx], b = pa.bn[i][C + idx];
      float m = pa.bn[i][2 * C + idx], v = pa.bn[i][3 * C + idx];
      float s = g * rsqrtf(v + 1e-5f);
      pa.bns[i][idx] = s;
      pa.bnb[i][idx] = b - m * s;
      return;
    }
    idx -= C;
  }
}

// ---------------- kNN: exact jax top_k replication (value desc, index asc) -----
// All keys live in REGISTERS (static indexing only). Per extraction:
//  - every thread: 1 LDS u64 read (the one slot that changed) + 3 u64 compares
//  - owner wave only: 6-step u64 butterfly; owner thread: static-unrolled rescan
__global__ __launch_bounds__(256) void knn_k(const float* __restrict__ geod,
                                             const void* __restrict__ loc,
                                             const int* __restrict__ modep,
                                             int* __restrict__ idxL,
                                             int* __restrict__ idxG) {
  int row = blockIdx.x;
  int b = row >> 11;
  int tid = threadIdx.x;
  int wid = tid >> 6, lane = tid & 63;
  int mode = *modep;
  const float* g = geod + (size_t)row * NPTS;

  float v[8];
  uint32_t amask = 0;
  float lmin = INFINITY;
  #pragma unroll
  for (int e = 0; e < 8; ++e) {
    int j = tid + 256 * e;
    v[e] = g[j];
    if (read_allow(loc, mode, b * NPTS + j)) amask |= (1u << e);
    lmin = fminf(lmin, v[e]);
  }
  __shared__ float sred[4];
  #pragma unroll
  for (int off = 32; off; off >>= 1) lmin = fminf(lmin, __shfl_xor(lmin, off));
  if (lane == 0) sred[wid] = lmin;
  __syncthreads();
  lmin = fminf(fminf(sred[0], sred[1]), fminf(sred[2], sred[3]));
  uint32_t smin = sortable_f32(lmin);

  __shared__ u64 skey[2][4];

  // runsel: exact top-K extraction over the block's 2048 register-held keys
  auto runsel = [&](u64 (&key)[8], int K, int* outp) {
    u64 tmax = key[0];
    #pragma unroll
    for (int e = 1; e < 8; ++e) tmax = tmax > key[e] ? tmax : key[e];
    // init: every wave publishes its wave max into slot parity 0
    {
      u64 m = tmax;
      #pragma unroll
      for (int off = 32; off; off >>= 1) {
        unsigned lo = __shfl_xor((unsigned)m, off);
        unsigned hi = __shfl_xor((unsigned)(m >> 32), off);
        u64 om = ((u64)hi << 32) | lo;
        m = m > om ? m : om;
      }
      if (lane == 0) skey[0][wid] = m;
    }
    __syncthreads();
    u64 wm0 = skey[0][0], wm1 = skey[0][1], wm2 = skey[0][2], wm3 = skey[0][3];
    int wprev = 0;
    for (int it = 0; it < K; ++it) {
      if (it) {   // fold in the single slot updated last iteration
        u64 nv = skey[(it - 1) & 1][wprev];
        wm0 = (wprev == 0) ? nv : wm0;
        wm1 = (wprev == 1) ? nv : wm1;
        wm2 = (wprev == 2) ? nv : wm2;
        wm3 = (wprev == 3) ? nv : wm3;
      }
      u64 M = wm0; int ws = 0;
      if (wm1 > M) { M = wm1; ws = 1; }
      if (wm2 > M) { M = wm2; ws = 2; }
      if (wm3 > M) { M = wm3; ws = 3; }
      int j = (NPTS - 1) - (int)(M & (u64)(NPTS - 1));
      if (tid == 0) outp[it] = j;
      if (wid == ws) {                 // only the owning wave recomputes
        if ((j & 255) == tid) {        // owner thread: static-indexed update
          int e = j >> 8;
          #pragma unroll
          for (int t = 0; t < 8; ++t) key[t] = (t == e) ? 0ull : key[t];
          tmax = key[0];
          #pragma unroll
          for (int t = 1; t < 8; ++t) tmax = tmax > key[t] ? tmax : key[t];
        }
        u64 m = tmax;
        #pragma unroll
        for (int off = 32; off; off >>= 1) {
          unsigned lo = __shfl_xor((unsigned)m, off);
          unsigned hi = __shfl_xor((unsigned)(m >> 32), off);
          u64 om = ((u64)hi << 32) | lo;
          m = m > om ? m : om;
        }
        if (lane == 0) skey[it & 1][ws] = m;
      }
      wprev = ws;
      __syncthreads();
    }
  };

  {  // local chain keys (allowed = local_idx), K=16
    u64 keyL[8];
    #pragma unroll
    for (int e = 0; e < 8; ++e) {
      int j = tid + 256 * e;
      uint32_t sv = sortable_f32(v[e]);
      uint32_t kl = (amask >> e & 1u) ? sv : smin;
      keyL[e] = ((u64)kl << 11) | (unsigned)(NPTS - 1 - j);
    }
    runsel(keyL, 16, idxL + (size_t)row * 16);
  }
  {  // global chain keys (allowed = ~local_idx), K=32 — built AFTER L to cut pressure
    u64 keyG[8];
    #pragma unroll
    for (int e = 0; e < 8; ++e) {
      int j = tid + 256 * e;
      uint32_t sv = sortable_f32(v[e]);
      uint32_t kg = (amask >> e & 1u) ? smin : sv;
      keyG[e] = ((u64)kg << 11) | (unsigned)(NPTS - 1 - j);
    }
    runsel(keyG, 32, idxG + (size_t)row * 32);
  }
}

// ---------------- fp32 tiled GEMM 64x64: C = A(MxK) * Bt(KxN2) ----------------
#define BM 64
#define BNC 64
#define BKC 16

__global__ __launch_bounds__(256) void gemm_k(const float* __restrict__ A, int lda,
                                              const float* __restrict__ Bt, int K, int N2,
                                              float* __restrict__ C, int ldc,
                                              const float* __restrict__ sc,
                                              const float* __restrict__ bi, int act) {
  __shared__ float As[BKC][BM + 4];   // row stride 272B = 16B-aligned
  __shared__ float Bs[BKC][BNC + 4];
  int tid = threadIdx.x;
  int tx = tid & 15, ty = tid >> 4;
  int m0 = blockIdx.x * BM, n0 = blockIdx.y * BNC;
  float acc[4][4] = {};
  for (int k0 = 0; k0 < K; k0 += BKC) {
    #pragma unroll
    for (int i = tid; i < BM * BKC; i += 256) {
      int kk = i & 15, mm = i >> 4;
      int kg = k0 + kk;
      As[kk][mm] = (kg < K) ? A[(size_t)(m0 + mm) * lda + kg] : 0.f;
    }
    #pragma unroll
    for (int i = tid; i < BKC * BNC; i += 256) {
      int nn = i & 63, kk = i >> 6;
      int kg = k0 + kk;
      Bs[kk][nn] = (kg < K) ? Bt[(size_t)kg * N2 + n0 + nn] : 0.f;
    }
    __syncthreads();
    #pragma unroll
    for (int k = 0; k < BKC; ++k) {
      float4 a4 = *(const float4*)&As[k][tx * 4];
      float4 b4 = *(const float4*)&Bs[k][ty * 4];
      float a[4] = {a4.x, a4.y, a4.z, a4.w};
      float bb[4] = {b4.x, b4.y, b4.z, b4.w};
      #pragma unroll
      for (int i2 = 0; i2 < 4; ++i2)
        #pragma unroll
        for (int j2 = 0; j2 < 4; ++j2)
          acc[i2][j2] = fmaf(a[i2], bb[j2], acc[i2][j2]);
    }
    __syncthreads();
  }
  #pragma unroll
  for (int i2 = 0; i2 < 4; ++i2) {
    int m = m0 + tx * 4 + i2;
    float4 o4;
    float* ov = (float*)&o4;
    #pragma unroll
    for (int j2 = 0; j2 < 4; ++j2) {
      int n = n0 + ty * 4 + j2;
      float vv = acc[i2][j2];
      if (act) {
        vv = fmaf(vv, sc[n], bi[n]);
        vv = lrelu(vv);
      }
      ov[j2] = vv;
    }
    *(float4*)&C[(size_t)m * ldc + n0 + ty * 4] = o4;
  }
}

// ------- big fp32 GEMM 128x64 tile, 8x4/thread, double-buffered LDS ------------
// r7 post-mortem: 128x128 (8x8 acc) ran at 204 VGPR -> 2 waves/SIMD, 11% occ,
// VALUBusy 59%. Halving the acc to 8x4 drops core pressure to ~76 VGPR ->
// 4 waves/SIMD + 2x grid, trading a little reuse for latency hiding.
#define GBM 128
#define GBN 64
#define GBK 16

__global__ __launch_bounds__(256) void gemmbig_k(const float* __restrict__ A, int lda,
                                                 const float* __restrict__ Bt, int K, int N2,
                                                 float* __restrict__ C, int ldc,
                                                 const float* __restrict__ sc,
                                                 const float* __restrict__ bi, int act) {
  __shared__ float As[2][GBK][GBM + 4];
  __shared__ float Bs[2][GBK][GBN + 4];
  int tid = threadIdx.x;
  int tx = tid & 15, ty = tid >> 4;
  int m0 = blockIdx.x * GBM, n0 = blockIdx.y * GBN;
  // staging indices (K multiple of 16: 128/512)
  int ar = tid >> 2;            // 0..63 (A rows, two halves)
  int ak = (tid & 3) * 4;       // 0,4,8,12
  int bk = tid >> 4;            // 0..15 (B k-rows)
  int bn = (tid & 15) * 4;      // 0..60
  const int nk = K / GBK;
  float4 a0, a1, b0;
  auto load_tile = [&](int kt) {
    int k0 = kt * GBK;
    a0 = *(const float4*)&A[(size_t)(m0 + ar) * lda + k0 + ak];
    a1 = *(const float4*)&A[(size_t)(m0 + 64 + ar) * lda + k0 + ak];
    b0 = *(const float4*)&Bt[(size_t)(k0 + bk) * N2 + n0 + bn];
  };
  auto store_tile = [&](int buf) {
    As[buf][ak + 0][ar] = a0.x; As[buf][ak + 1][ar] = a0.y;
    As[buf][ak + 2][ar] = a0.z; As[buf][ak + 3][ar] = a0.w;
    As[buf][ak + 0][64 + ar] = a1.x; As[buf][ak + 1][64 + ar] = a1.y;
    As[buf][ak + 2][64 + ar] = a1.z; As[buf][ak + 3][64 + ar] = a1.w;
    *(float4*)&Bs[buf][bk][bn] = b0;
  };
  float acc[2][4][4] = {};
  load_tile(0);
  store_tile(0);
  __syncthreads();
  for (int kt = 0; kt < nk; ++kt) {
    int cur = kt & 1;
    if (kt + 1 < nk) load_tile(kt + 1);
    #pragma unroll
    for (int k = 0; k < GBK; ++k) {
      float a[2][4], b[4];
      *(float4*)a[0] = *(const float4*)&As[cur][k][tx * 4];
      *(float4*)a[1] = *(const float4*)&As[cur][k][64 + tx * 4];
      *(float4*)b = *(const float4*)&Bs[cur][k][ty * 4];
      #pragma unroll
      for (int im = 0; im < 2; ++im)
        #pragma unroll
        for (int i = 0; i < 4; ++i)
          #pragma unroll
          for (int j = 0; j < 4; ++j)
            acc[im][i][j] = fmaf(a[im][i], b[j], acc[im][i][j]);
    }
    if (kt + 1 < nk) store_tile(1 - cur);
    __syncthreads();
  }
  #pragma unroll
  for (int im = 0; im < 2; ++im)
    #pragma unroll
    for (int i = 0; i < 4; ++i) {
      int m = m0 + im * 64 + tx * 4 + i;
      int nbase = n0 + ty * 4;
      float4 o4;
      float* ov = (float*)&o4;
      #pragma unroll
      for (int j = 0; j < 4; ++j) {
        float vv = acc[im][i][j];
        if (act) {
          vv = fmaf(vv, sc[nbase + j], bi[nbase + j]);
          vv = lrelu(vv);
        }
        ov[j] = vv;
      }
      *(float4*)&C[(size_t)m * ldc + nbase] = o4;
    }
}

// ---------------- gather-max + BN + leaky: one wave per point ------------------
// vectorized per-lane channels: float4 for O>=256, float2 for O==128, scalar O==64
template<int K, int O>
__global__ __launch_bounds__(256) void gather_k(const float* __restrict__ z,
                                                const int* __restrict__ idx,
                                                const float* __restrict__ scale,
                                                const float* __restrict__ bias,
                                                float* __restrict__ outp) {
  constexpr int LDZ = 2 * O;
  int wid = threadIdx.x >> 6, lane = threadIdx.x & 63;
  int point = (blockIdx.x << 2) + wid;
  int b = point >> 11;
  const int* ip = idx + (size_t)point * K;
  int jj[K];
  #pragma unroll
  for (int k = 0; k < K; ++k) jj[k] = ip[k];
  if constexpr (O >= 256) {
    int c = lane * 4;                       // O==256: one float4 iter covers all
    float4 mx = {-INFINITY, -INFINITY, -INFINITY, -INFINITY};
    float4 mn = {INFINITY, INFINITY, INFINITY, INFINITY};
    #pragma unroll
    for (int k = 0; k < K; ++k) {
      float4 v = *(const float4*)&z[(size_t)((b << 11) + jj[k]) * LDZ + c];
      mx.x = fmaxf(mx.x, v.x); mx.y = fmaxf(mx.y, v.y);
      mx.z = fmaxf(mx.z, v.z); mx.w = fmaxf(mx.w, v.w);
      mn.x = fminf(mn.x, v.x); mn.y = fminf(mn.y, v.y);
      mn.z = fminf(mn.z, v.z); mn.w = fminf(mn.w, v.w);
    }
    float4 zc = *(const float4*)&z[(size_t)point * LDZ + O + c];
    float4 s = *(const float4*)&scale[c];
    float4 bb = *(const float4*)&bias[c];
    float4 o;
    o.x = lrelu(fmaf((s.x >= 0.f ? mx.x : mn.x) + zc.x, s.x, bb.x));
    o.y = lrelu(fmaf((s.y >= 0.f ? mx.y : mn.y) + zc.y, s.y, bb.y));
    o.z = lrelu(fmaf((s.z >= 0.f ? mx.z : mn.z) + zc.z, s.z, bb.z));
    o.w = lrelu(fmaf((s.w >= 0.f ? mx.w : mn.w) + zc.w, s.w, bb.w));
    *(float4*)&outp[(size_t)point * 512 + c] = o;
  } else if constexpr (O == 128) {
    int c = lane * 2;
    float2 mx = {-INFINITY, -INFINITY}, mn = {INFINITY, INFINITY};
    #pragma unroll
    for (int k = 0; k < K; ++k) {
      float2 v = *(const float2*)&z[(size_t)((b << 11) + jj[k]) * LDZ + c];
      mx.x = fmaxf(mx.x, v.x); mx.y = fmaxf(mx.y, v.y);
      mn.x = fminf(mn.x, v.x); mn.y = fminf(mn.y, v.y);
    }
    float2 zc = *(const float2*)&z[(size_t)point * LDZ + O + c];
    float2 s = *(const float2*)&scale[c];
    float2 bb = *(const float2*)&bias[c];
    float2 o;
    o.x = lrelu(fmaf((s.x >= 0.f ? mx.x : mn.x) + zc.x, s.x, bb.x));
    o.y = lrelu(fmaf((s.y >= 0.f ? mx.y : mn.y) + zc.y, s.y, bb.y));
    *(float2*)&outp[(size_t)point * 512 + c] = o;
  } else {
    int c = lane;
    float mx = -INFINITY, mn = INFINITY;
    #pragma unroll
    for (int k = 0; k < K; ++k) {
      float v = z[(size_t)((b << 11) + jj[k]) * LDZ + c];
      mx = fmaxf(mx, v);
      mn = fminf(mn, v);
    }
    float zc = z[(size_t)point * LDZ + O + c];
    float s = scale[c], bb = bias[c];
    float t = fmaf((s >= 0.f ? mx : mn) + zc, s, bb);
    outp[(size_t)point * 512 + c] = lrelu(t);
  }
}

// ---------------- xm = local_idx ? xcatL : xcatG ------------------------------
__global__ __launch_bounds__(256) void select_k(const float* __restrict__ xl,
                                                const float* __restrict__ xg,
                                                const void* __restrict__ loc,
                                                const int* __restrict__ modep,
                                                float* __restrict__ xm) {
  int i = blockIdx.x * 256 + threadIdx.x;   // over NROWS*128 float4
  int row = i >> 7;
  int mode = *modep;
  bool l = read_allow(loc, mode, row);
  const float4* s = (const float4*)(l ? xl : xg);
  ((float4*)xm)[i] = s[i];
}

// ---------------- per-(b,channel) max & mean over n ---------------------------
__global__ __launch_bounds__(256) void reduce_np_k(const float* __restrict__ y,
                                                   float* __restrict__ p) {
  int b = blockIdx.x >> 4, cb = blockIdx.x & 15;
  int wid = threadIdx.x >> 6, lane = threadIdx.x & 63;
  int c = cb * 64 + lane;
  float mx = -INFINITY, sm = 0.f;
  for (int n = wid; n < NPTS; n += 4) {
    float v = y[((size_t)(b * NPTS + n)) * 1024 + c];
    mx = fmaxf(mx, v);
    sm += v;
  }
  __shared__ float smx[4][64], ssm[4][64];
  smx[wid][lane] = mx;
  ssm[wid][lane] = sm;
  __syncthreads();
  if (wid == 0) {
    #pragma unroll
    for (int w = 1; w < 4; ++w) { mx = fmaxf(mx, smx[w][lane]); sm += ssm[w][lane]; }
    p[b * 2048 + c] = mx;
    p[b * 2048 + 1024 + c] = sm * (1.f / 2048.f);
  }
}

// ---------------- MLP layer kernels: one wave per output neuron ---------------
__global__ __launch_bounds__(256) void mlp1_k(const float* __restrict__ p,
                                              const float* __restrict__ w,
                                              const float* __restrict__ s10,
                                              const float* __restrict__ b10,
                                              float* __restrict__ h1) {
  int o = (blockIdx.x << 2) + (threadIdx.x >> 6);
  int lane = threadIdx.x & 63;
  const float4* wr = (const float4*)(w + (size_t)o * 2048);
  float acc[NB] = {};
  for (int i = lane; i < 512; i += 64) {
    float4 wv = wr[i];
    #pragma unroll
    for (int b = 0; b < NB; ++b) {
      float4 pv = ((const float4*)(p + b * 2048))[i];
      acc[b] += wv.x * pv.x + wv.y * pv.y + wv.z * pv.z + wv.w * pv.w;
    }
  }
  #pragma unroll
  for (int off = 32; off; off >>= 1)
    #pragma unroll
    for (int b = 0; b < NB; ++b) acc[b] += __shfl_xor(acc[b], off);
  if (lane == 0) {
    float sc = s10[o], bc = b10[o];
    #pragma unroll
    for (int b = 0; b < NB; ++b) h1[b * 512 + o] = lrelu(fmaf(acc[b], sc, bc));
  }
}

__global__ __launch_bounds__(256) void mlp2_k(const float* __restrict__ h1,
                                              const float* __restrict__ w,
                                              const float* __restrict__ l2b,
                                              const float* __restrict__ s11,
                                              const float* __restrict__ b11,
                                              float* __restrict__ h2) {
  int o = (blockIdx.x << 2) + (threadIdx.x >> 6);
  int lane = threadIdx.x & 63;
  const float4* wr = (const float4*)(w + (size_t)o * 512);
  float acc[NB] = {};
  for (int i = lane; i < 128; i += 64) {
    float4 wv = wr[i];
    #pragma unroll
    for (int b = 0; b < NB; ++b) {
      float4 pv = ((const float4*)(h1 + b * 512))[i];
      acc[b] += wv.x * pv.x + wv.y * pv.y + wv.z * pv.z + wv.w * pv.w;
    }
  }
  #pragma unroll
  for (int off = 32; off; off >>= 1)
    #pragma unroll
    for (int b = 0; b < NB; ++b) acc[b] += __shfl_xor(acc[b], off);
  if (lane == 0) {
    float bl = l2b[o], sc = s11[o], bc = b11[o];
    #pragma unroll
    for (int b = 0; b < NB; ++b) h2[b * 256 + o] = lrelu(fmaf(acc[b] + bl, sc, bc));
  }
}

__global__ __launch_bounds__(256) void mlp3_k(const float* __restrict__ h2,
                                              const float* __restrict__ w,
                                              const float* __restrict__ l3b,
                                              float* __restrict__ outp) {
  int o = (blockIdx.x << 2) + (threadIdx.x >> 6);
  int lane = threadIdx.x & 63;
  if (o >= 40) return;
  const float4* wr = (const float4*)(w + (size_t)o * 256);
  float acc[NB] = {};
  for (int i = lane; i < 64; i += 64) {
    float4 wv = wr[i];
    #pragma unroll
    for (int b = 0; b < NB; ++b) {
      float4 pv = ((const float4*)(h2 + b * 256))[i];
      acc[b] += wv.x * pv.x + wv.y * pv.y + wv.z * pv.z + wv.w * pv.w;
    }
  }
  #pragma unroll
  for (int off = 32; off; off >>= 1)
    #pragma unroll
    for (int b = 0; b < NB; ++b) acc[b] += __shfl_xor(acc[b], off);
  if (lane == 0) {
    float bl = l3b[o];
    #pragma unroll
    for (int b = 0; b < NB; ++b) outp[b * 40 + o] = acc[b] + bl;
  }
}

// ---------------- host orchestration ------------------------------------------
extern "C" void kernel_launch(void* const* d_in, const int* in_sizes, int n_in,
                              void* d_out, int out_size, void* d_ws, size_t ws_size,
                              hipStream_t stream) {
  const float* x = (const float*)d_in[0];
  const void* loc = d_in[1];
  const float* geod = (const float*)d_in[2];
  const float* w[9];
  for (int i = 0; i < 9; ++i) w[i] = (const float*)d_in[3 + i];
  const float* bn[11];
  for (int i = 0; i < 11; ++i) bn[i] = (const float*)d_in[12 + i];
  const float* l1w = (const float*)d_in[23];
  const float* l2w = (const float*)d_in[24];
  const float* l2b = (const float*)d_in[25];
  const float* l3w = (const float*)d_in[26];
  const float* l3b = (const float*)d_in[27];
  float* outp = (float*)d_out;

  char* base = (char*)d_ws;
  size_t off = 0;
  auto alloc = [&](size_t bytes) -> void* {
    void* p = base + off;
    off += (bytes + 255) & ~(size_t)255;
    return p;
  };
  int* mode = (int*)alloc(4);
  float* x0 = (float*)alloc((size_t)NROWS * 3 * 4);
  int* idxL = (int*)alloc((size_t)NROWS * 16 * 4);
  int* idxG = (int*)alloc((size_t)NROWS * 32 * 4);
  static const int Oc[9] = {64, 64, 128, 256, 64, 64, 128, 256, 1024};
  static const int Cc[9] = {3, 64, 64, 128, 3, 64, 64, 128, 512};
  float* wt[9];
  for (int l = 0; l < 9; ++l) {
    int n2 = (l == 8) ? Oc[l] : 2 * Oc[l];
    wt[l] = (float*)alloc((size_t)Cc[l] * n2 * 4);
  }
  static const int bc[11] = {64, 64, 128, 256, 64, 64, 128, 256, 1024, 512, 256};
  float *bns[11], *bnb[11];
  for (int i = 0; i < 11; ++i) {
    bns[i] = (float*)alloc((size_t)bc[i] * 4);
    bnb[i] = (float*)alloc((size_t)bc[i] * 4);
  }
  float* z = (float*)alloc((size_t)NROWS * 1024 * 4);      // reused: conv z / layer-9 y
  float* xcatL = (float*)alloc((size_t)NROWS * 512 * 4);
  float* xcatG = (float*)alloc((size_t)NROWS * 512 * 4);
  float* xm = (float*)alloc((size_t)NROWS * 512 * 4);
  float* pbuf = (float*)alloc((size_t)NB * 2048 * 4);
  float* h1 = (float*)alloc((size_t)NB * 512 * 4);
  float* h2 = (float*)alloc((size_t)NB * 256 * 4);

  detect_mode_k<<<1, 256, 0, stream>>>((const uint32_t*)loc, mode);

  PrepArgs pa;
  pa.x = x; pa.x0 = x0;
  for (int l = 0; l < 9; ++l) { pa.w[l] = w[l]; pa.wt[l] = wt[l]; pa.O[l] = Oc[l]; pa.C[l] = Cc[l]; }
  for (int i = 0; i < 11; ++i) { pa.bn[i] = bn[i]; pa.bns[i] = bns[i]; pa.bnb[i] = bnb[i]; pa.bc[i] = bc[i]; }
  int total = NROWS * 3;
  for (int l = 0; l < 9; ++l) total += Cc[l] * ((l == 8) ? Oc[l] : 2 * Oc[l]);
  for (int i = 0; i < 11; ++i) total += bc[i];
  prep_k<<<(total + 255) / 256, 256, 0, stream>>>(pa);

  knn_k<<<NROWS, 256, 0, stream>>>(geod, loc, mode, idxL, idxG);

  auto gemm = [&](const float* A, int lda, const float* Bt, int K, int N2, float* C, int ldc,
                  const float* sc, const float* bi, int act) {
    if (N2 >= 512) {
      dim3 grid(NROWS / GBM, N2 / GBN);
      gemmbig_k<<<grid, 256, 0, stream>>>(A, lda, Bt, K, N2, C, ldc, sc, bi, act);
    } else {
      dim3 grid(NROWS / BM, N2 / BNC);
      gemm_k<<<grid, 256, 0, stream>>>(A, lda, Bt, K, N2, C, ldc, sc, bi, act);
    }
  };
  auto gather = [&](int K, int O, const int* idx, const float* sc, const float* bi, float* op) {
    dim3 grid(NROWS / 4);
    if (K == 16) {
      if (O == 64)       gather_k<16, 64><<<grid, 256, 0, stream>>>(z, idx, sc, bi, op);
      else if (O == 128) gather_k<16, 128><<<grid, 256, 0, stream>>>(z, idx, sc, bi, op);
      else               gather_k<16, 256><<<grid, 256, 0, stream>>>(z, idx, sc, bi, op);
    } else {
      if (O == 64)       gather_k<32, 64><<<grid, 256, 0, stream>>>(z, idx, sc, bi, op);
      else if (O == 128) gather_k<32, 128><<<grid, 256, 0, stream>>>(z, idx, sc, bi, op);
      else               gather_k<32, 256><<<grid, 256, 0, stream>>>(z, idx, sc, bi, op);
    }
  };

  static const int coff[4] = {0, 64, 128, 256};
  for (int l = 0; l < 4; ++l) {   // local chain (K=16, w1-4, bn1-4)
    const float* A = (l == 0) ? x0 : (xcatL + coff[l - 1]);
    int lda = (l == 0) ? 3 : 512;
    gemm(A, lda, wt[l], Cc[l], 2 * Oc[l], z, 2 * Oc[l], nullptr, nullptr, 0);
    gather(16, Oc[l], idxL, bns[l], bnb[l], xcatL + coff[l]);
  }
  for (int l = 0; l < 4; ++l) {   // global chain (K=32, w5-8, bn5-8)
    const float* A = (l == 0) ? x0 : (xcatG + coff[l - 1]);
    int lda = (l == 0) ? 3 : 512;
    gemm(A, lda, wt[4 + l], Cc[4 + l], 2 * Oc[4 + l], z, 2 * Oc[4 + l], nullptr, nullptr, 0);
    gather(32, Oc[4 + l], idxG, bns[4 + l], bnb[4 + l], xcatG + coff[l]);
  }

  select_k<<<(NROWS * 512 / 4) / 256, 256, 0, stream>>>(xcatL, xcatG, loc, mode, xm);
  gemm(xm, 512, wt[8], 512, 1024, z, 1024, bns[8], bnb[8], 1);   // layer 9 + BN9 + leaky fused
  reduce_np_k<<<NB * 16, 256, 0, stream>>>(z, pbuf);
  mlp1_k<<<128, 256, 0, stream>>>(pbuf, l1w, bns[9], bnb[9], h1);
  mlp2_k<<<64, 256, 0, stream>>>(h1, l2w, l2b, bns[10], bnb[10], h2);
  mlp3_k<<<10, 256, 0, stream>>>(h2, l3w, l3b, outp);
}

// Round 11
// 851.453 us; speedup vs baseline: 5.2584x; 1.0089x over previous
//
#include <hip/hip_runtime.h>
#include <stdint.h>

#define NPTS 2048
#define NB 4
#define NROWS (NB * NPTS)
#define LNEG 0.2f

typedef unsigned long long u64;

static __device__ __forceinline__ uint32_t sortable_f32(float f) {
  uint32_t u = __float_as_uint(f);
  return u ^ ((u >> 31) ? 0xFFFFFFFFu : 0x80000000u);
}

static __device__ __forceinline__ float lrelu(float t) { return t >= 0.f ? t : LNEG * t; }

// ---------------- local_idx dtype detect (bool u8 vs i32 vs i64) ----------------
__global__ void detect_mode_k(const uint32_t* __restrict__ loc, int* __restrict__ mode) {
  __shared__ uint32_t mAll, mOdd;
  if (threadIdx.x == 0) { mAll = 0u; mOdd = 0u; }
  __syncthreads();
  uint32_t a = 0u, o = 0u;
  for (int i = threadIdx.x; i < 2048; i += 256) {  // 8192 bytes: safe for every mode
    uint32_t v = loc[i];
    a = a > v ? a : v;
    if (i & 1) o = o > v ? o : v;
  }
  atomicMax(&mAll, a);
  atomicMax(&mOdd, o);
  __syncthreads();
  if (threadIdx.x == 0) {
    int m;
    if (mAll > 1u) m = 0;        // packed 1-byte bool
    else if (mOdd == 0u) m = 2;  // int64 (odd u32 words all zero)
    else m = 1;                  // int32
    *mode = m;
  }
}

__device__ __forceinline__ bool read_allow(const void* loc, int mode, int i) {
  if (mode == 0) return ((const uint8_t*)loc)[i] != 0;
  if (mode == 1) return ((const int*)loc)[i] != 0;
  return ((const uint32_t*)loc)[(size_t)i * 2] != 0;  // little-endian low word
}

// ---------------- prep: x transpose, weight transforms, BN fold ----------------
struct PrepArgs {
  const float* x; float* x0;
  const float* w[9]; float* wt[9];
  int O[9], C[9];
  const float* bn[11]; float* bns[11]; float* bnb[11];
  int bc[11];
};

__global__ void prep_k(PrepArgs pa) {
  int idx = blockIdx.x * 256 + threadIdx.x;
  if (idx < NROWS * 3) {               // x (B,3,N) -> x0 (B*N, 3)
    int c = idx % 3, r = idx / 3;
    int b = r >> 11, n = r & (NPTS - 1);
    pa.x0[idx] = pa.x[((size_t)b * 3 + c) * NPTS + n];
    return;
  }
  idx -= NROWS * 3;
  #pragma unroll
  for (int l = 0; l < 9; ++l) {
    int O = pa.O[l], C = pa.C[l];
    int n2 = (l == 8) ? O : 2 * O;
    int sz = C * n2;
    if (idx < sz) {
      int o = idx % n2, c = idx / n2;
      float v;
      if (l == 8) v = pa.w[l][(size_t)o * C + c];                     // plain transpose of w9
      else if (o < O) v = pa.w[l][(size_t)o * 2 * C + c];             // wA
      else v = pa.w[l][(size_t)(o - O) * 2 * C + C + c]
             - pa.w[l][(size_t)(o - O) * 2 * C + c];                  // wB - wA
      pa.wt[l][(size_t)c * n2 + o] = v;
      return;
    }
    idx -= sz;
  }
  #pragma unroll
  for (int i = 0; i < 11; ++i) {
    int C = pa.bc[i];
    if (idx < C) {
      float g = pa.bn[i][idx], b = pa.bn[i][C + idx];
      float m = pa.bn[i][2 * C + idx], v = pa.bn[i][3 * C + idx];
      float s = g * rsqrtf(v + 1e-5f);
      pa.bns[i][idx] = s;
      pa.bnb[i][idx] = b - m * s;
      return;
    }
    idx -= C;
  }
}

// ---------------- kNN: exact jax top_k replication (value desc, index asc) -----
// ONE WAVE PER TASK (task = row x {local,global}). 32 keys/lane, all in
// registers with static indexing; extraction = 6-step u64 shfl butterfly +
// owner-lane static-unrolled zero+rescan. No barriers, no LDS.
// r8 post-mortem: block-wide scheme showed VGPR=28 -> key arrays lived in
// scratch; 48 block barriers serialized everything (197us, VALUBusy 50%).
__global__ __launch_bounds__(256) void knn_k(const float* __restrict__ geod,
                                             const void* __restrict__ loc,
                                             const int* __restrict__ modep,
                                             int* __restrict__ idxL,
                                             int* __restrict__ idxG) {
  int wid = threadIdx.x >> 6, lane = threadIdx.x & 63;
  int task = (blockIdx.x << 2) + wid;          // 16384 tasks
  int row = task >> 1;
  bool isG = task & 1;
  int b = row >> 11;
  int mode = *modep;
  const float* g = geod + (size_t)row * NPTS;

  // pass 1: row min (monotone under sortable_f32, computed on floats)
  float lmin = INFINITY;
  #pragma unroll
  for (int e = 0; e < 32; ++e) lmin = fminf(lmin, g[lane + 64 * e]);
  #pragma unroll
  for (int off = 32; off; off >>= 1) lmin = fminf(lmin, __shfl_xor(lmin, off));
  uint32_t smin = sortable_f32(lmin);

  // pass 2: build keys (reload geod — row is L1-hot, keeps VGPR peak ~90)
  u64 key[32];
  #pragma unroll
  for (int e = 0; e < 32; ++e) {
    int j = lane + 64 * e;
    bool allow = read_allow(loc, mode, b * NPTS + j);
    if (isG) allow = !allow;
    uint32_t kv = allow ? sortable_f32(g[j]) : smin;
    key[e] = ((u64)kv << 11) | (unsigned)(NPTS - 1 - j);
  }
  u64 tmax = key[0];
  #pragma unroll
  for (int e = 1; e < 32; ++e) tmax = tmax > key[e] ? tmax : key[e];

  int K = isG ? 32 : 16;
  int* outp = isG ? (idxG + (size_t)row * 32) : (idxL + (size_t)row * 16);
  for (int it = 0; it < K; ++it) {
    u64 m = tmax;
    #pragma unroll
    for (int off = 32; off; off >>= 1) {
      unsigned lo = __shfl_xor((unsigned)m, off);
      unsigned hi = __shfl_xor((unsigned)(m >> 32), off);
      u64 om = ((u64)hi << 32) | lo;
      m = m > om ? m : om;
    }
    int j = (NPTS - 1) - (int)(m & (u64)(NPTS - 1));
    if (lane == 0) outp[it] = j;
    if (lane == (j & 63)) {            // owner lane: zero + rescan, all static
      int e = j >> 6;
      u64 nm = 0;
      #pragma unroll
      for (int t = 0; t < 32; ++t) {
        key[t] = (t == e) ? 0ull : key[t];
        nm = nm > key[t] ? nm : key[t];
      }
      tmax = nm;
    }
  }
}

// ---------------- fp32 tiled GEMM 64x64: C = A(MxK) * Bt(KxN2) ----------------
#define BM 64
#define BNC 64
#define BKC 16

__global__ __launch_bounds__(256) void gemm_k(const float* __restrict__ A, int lda,
                                              const float* __restrict__ Bt, int K, int N2,
                                              float* __restrict__ C, int ldc,
                                              const float* __restrict__ sc,
                                              const float* __restrict__ bi, int act) {
  __shared__ float As[BKC][BM + 4];   // row stride 272B = 16B-aligned
  __shared__ float Bs[BKC][BNC + 4];
  int tid = threadIdx.x;
  int tx = tid & 15, ty = tid >> 4;
  int m0 = blockIdx.x * BM, n0 = blockIdx.y * BNC;
  float acc[4][4] = {};
  for (int k0 = 0; k0 < K; k0 += BKC) {
    #pragma unroll
    for (int i = tid; i < BM * BKC; i += 256) {
      int kk = i & 15, mm = i >> 4;
      int kg = k0 + kk;
      As[kk][mm] = (kg < K) ? A[(size_t)(m0 + mm) * lda + kg] : 0.f;
    }
    #pragma unroll
    for (int i = tid; i < BKC * BNC; i += 256) {
      int nn = i & 63, kk = i >> 6;
      int kg = k0 + kk;
      Bs[kk][nn] = (kg < K) ? Bt[(size_t)kg * N2 + n0 + nn] : 0.f;
    }
    __syncthreads();
    #pragma unroll
    for (int k = 0; k < BKC; ++k) {
      float4 a4 = *(const float4*)&As[k][tx * 4];
      float4 b4 = *(const float4*)&Bs[k][ty * 4];
      float a[4] = {a4.x, a4.y, a4.z, a4.w};
      float bb[4] = {b4.x, b4.y, b4.z, b4.w};
      #pragma unroll
      for (int i2 = 0; i2 < 4; ++i2)
        #pragma unroll
        for (int j2 = 0; j2 < 4; ++j2)
          acc[i2][j2] = fmaf(a[i2], bb[j2], acc[i2][j2]);
    }
    __syncthreads();
  }
  #pragma unroll
  for (int i2 = 0; i2 < 4; ++i2) {
    int m = m0 + tx * 4 + i2;
    float4 o4;
    float* ov = (float*)&o4;
    #pragma unroll
    for (int j2 = 0; j2 < 4; ++j2) {
      int n = n0 + ty * 4 + j2;
      float vv = acc[i2][j2];
      if (act) {
        vv = fmaf(vv, sc[n], bi[n]);
        vv = lrelu(vv);
      }
      ov[j2] = vv;
    }
    *(float4*)&C[(size_t)m * ldc + n0 + ty * 4] = o4;
  }
}

// ------- big fp32 GEMM 128x64 tile, 8x4/thread, double-buffered LDS ------------
#define GBM 128
#define GBN 64
#define GBK 16

__global__ __launch_bounds__(256) void gemmbig_k(const float* __restrict__ A, int lda,
                                                 const float* __restrict__ Bt, int K, int N2,
                                                 float* __restrict__ C, int ldc,
                                                 const float* __restrict__ sc,
                                                 const float* __restrict__ bi, int act) {
  __shared__ float As[2][GBK][GBM + 4];
  __shared__ float Bs[2][GBK][GBN + 4];
  int tid = threadIdx.x;
  int tx = tid & 15, ty = tid >> 4;
  int m0 = blockIdx.x * GBM, n0 = blockIdx.y * GBN;
  // staging indices (K multiple of 16: 128/512)
  int ar = tid >> 2;            // 0..63 (A rows, two halves)
  int ak = (tid & 3) * 4;       // 0,4,8,12
  int bk = tid >> 4;            // 0..15 (B k-rows)
  int bn = (tid & 15) * 4;      // 0..60
  const int nk = K / GBK;
  float4 a0, a1, b0;
  auto load_tile = [&](int kt) {
    int k0 = kt * GBK;
    a0 = *(const float4*)&A[(size_t)(m0 + ar) * lda + k0 + ak];
    a1 = *(const float4*)&A[(size_t)(m0 + 64 + ar) * lda + k0 + ak];
    b0 = *(const float4*)&Bt[(size_t)(k0 + bk) * N2 + n0 + bn];
  };
  auto store_tile = [&](int buf) {
    As[buf][ak + 0][ar] = a0.x; As[buf][ak + 1][ar] = a0.y;
    As[buf][ak + 2][ar] = a0.z; As[buf][ak + 3][ar] = a0.w;
    As[buf][ak + 0][64 + ar] = a1.x; As[buf][ak + 1][64 + ar] = a1.y;
    As[buf][ak + 2][64 + ar] = a1.z; As[buf][ak + 3][64 + ar] = a1.w;
    *(float4*)&Bs[buf][bk][bn] = b0;
  };
  float acc[2][4][4] = {};
  load_tile(0);
  store_tile(0);
  __syncthreads();
  for (int kt = 0; kt < nk; ++kt) {
    int cur = kt & 1;
    if (kt + 1 < nk) load_tile(kt + 1);
    #pragma unroll
    for (int k = 0; k < GBK; ++k) {
      float a[2][4], b[4];
      *(float4*)a[0] = *(const float4*)&As[cur][k][tx * 4];
      *(float4*)a[1] = *(const float4*)&As[cur][k][64 + tx * 4];
      *(float4*)b = *(const float4*)&Bs[cur][k][ty * 4];
      #pragma unroll
      for (int im = 0; im < 2; ++im)
        #pragma unroll
        for (int i = 0; i < 4; ++i)
          #pragma unroll
          for (int j = 0; j < 4; ++j)
            acc[im][i][j] = fmaf(a[im][i], b[j], acc[im][i][j]);
    }
    if (kt + 1 < nk) store_tile(1 - cur);
    __syncthreads();
  }
  #pragma unroll
  for (int im = 0; im < 2; ++im)
    #pragma unroll
    for (int i = 0; i < 4; ++i) {
      int m = m0 + im * 64 + tx * 4 + i;
      int nbase = n0 + ty * 4;
      float4 o4;
      float* ov = (float*)&o4;
      #pragma unroll
      for (int j = 0; j < 4; ++j) {
        float vv = acc[im][i][j];
        if (act) {
          vv = fmaf(vv, sc[nbase + j], bi[nbase + j]);
          vv = lrelu(vv);
        }
        ov[j] = vv;
      }
      *(float4*)&C[(size_t)m * ldc + nbase] = o4;
    }
}

// ---------------- gather-max + BN + leaky: one wave per point ------------------
// vectorized per-lane channels: float4 for O>=256, float2 for O==128, scalar O==64
template<int K, int O>
__global__ __launch_bounds__(256) void gather_k(const float* __restrict__ z,
                                                const int* __restrict__ idx,
                                                const float* __restrict__ scale,
                                                const float* __restrict__ bias,
                                                float* __restrict__ outp) {
  constexpr int LDZ = 2 * O;
  int wid = threadIdx.x >> 6, lane = threadIdx.x & 63;
  int point = (blockIdx.x << 2) + wid;
  int b = point >> 11;
  const int* ip = idx + (size_t)point * K;
  int jj[K];
  #pragma unroll
  for (int k = 0; k < K; ++k) jj[k] = ip[k];
  if constexpr (O >= 256) {
    int c = lane * 4;                       // O==256: one float4 iter covers all
    float4 mx = {-INFINITY, -INFINITY, -INFINITY, -INFINITY};
    float4 mn = {INFINITY, INFINITY, INFINITY, INFINITY};
    #pragma unroll
    for (int k = 0; k < K; ++k) {
      float4 v = *(const float4*)&z[(size_t)((b << 11) + jj[k]) * LDZ + c];
      mx.x = fmaxf(mx.x, v.x); mx.y = fmaxf(mx.y, v.y);
      mx.z = fmaxf(mx.z, v.z); mx.w = fmaxf(mx.w, v.w);
      mn.x = fminf(mn.x, v.x); mn.y = fminf(mn.y, v.y);
      mn.z = fminf(mn.z, v.z); mn.w = fminf(mn.w, v.w);
    }
    float4 zc = *(const float4*)&z[(size_t)point * LDZ + O + c];
    float4 s = *(const float4*)&scale[c];
    float4 bb = *(const float4*)&bias[c];
    float4 o;
    o.x = lrelu(fmaf((s.x >= 0.f ? mx.x : mn.x) + zc.x, s.x, bb.x));
    o.y = lrelu(fmaf((s.y >= 0.f ? mx.y : mn.y) + zc.y, s.y, bb.y));
    o.z = lrelu(fmaf((s.z >= 0.f ? mx.z : mn.z) + zc.z, s.z, bb.z));
    o.w = lrelu(fmaf((s.w >= 0.f ? mx.w : mn.w) + zc.w, s.w, bb.w));
    *(float4*)&outp[(size_t)point * 512 + c] = o;
  } else if constexpr (O == 128) {
    int c = lane * 2;
    float2 mx = {-INFINITY, -INFINITY}, mn = {INFINITY, INFINITY};
    #pragma unroll
    for (int k = 0; k < K; ++k) {
      float2 v = *(const float2*)&z[(size_t)((b << 11) + jj[k]) * LDZ + c];
      mx.x = fmaxf(mx.x, v.x); mx.y = fmaxf(mx.y, v.y);
      mn.x = fminf(mn.x, v.x); mn.y = fminf(mn.y, v.y);
    }
    float2 zc = *(const float2*)&z[(size_t)point * LDZ + O + c];
    float2 s = *(const float2*)&scale[c];
    float2 bb = *(const float2*)&bias[c];
    float2 o;
    o.x = lrelu(fmaf((s.x >= 0.f ? mx.x : mn.x) + zc.x, s.x, bb.x));
    o.y = lrelu(fmaf((s.y >= 0.f ? mx.y : mn.y) + zc.y, s.y, bb.y));
    *(float2*)&outp[(size_t)point * 512 + c] = o;
  } else {
    int c = lane;
    float mx = -INFINITY, mn = INFINITY;
    #pragma unroll
    for (int k = 0; k < K; ++k) {
      float v = z[(size_t)((b << 11) + jj[k]) * LDZ + c];
      mx = fmaxf(mx, v);
      mn = fminf(mn, v);
    }
    float zc = z[(size_t)point * LDZ + O + c];
    float s = scale[c], bb = bias[c];
    float t = fmaf((s >= 0.f ? mx : mn) + zc, s, bb);
    outp[(size_t)point * 512 + c] = lrelu(t);
  }
}

// ---------------- xm = local_idx ? xcatL : xcatG ------------------------------
__global__ __launch_bounds__(256) void select_k(const float* __restrict__ xl,
                                                const float* __restrict__ xg,
                                                const void* __restrict__ loc,
                                                const int* __restrict__ modep,
                                                float* __restrict__ xm) {
  int i = blockIdx.x * 256 + threadIdx.x;   // over NROWS*128 float4
  int row = i >> 7;
  int mode = *modep;
  bool l = read_allow(loc, mode, row);
  const float4* s = (const float4*)(l ? xl : xg);
  ((float4*)xm)[i] = s[i];
}

// ---------------- per-(b,channel) max & mean over n ---------------------------
__global__ __launch_bounds__(256) void reduce_np_k(const float* __restrict__ y,
                                                   float* __restrict__ p) {
  int b = blockIdx.x >> 4, cb = blockIdx.x & 15;
  int wid = threadIdx.x >> 6, lane = threadIdx.x & 63;
  int c = cb * 64 + lane;
  float mx = -INFINITY, sm = 0.f;
  for (int n = wid; n < NPTS; n += 4) {
    float v = y[((size_t)(b * NPTS + n)) * 1024 + c];
    mx = fmaxf(mx, v);
    sm += v;
  }
  __shared__ float smx[4][64], ssm[4][64];
  smx[wid][lane] = mx;
  ssm[wid][lane] = sm;
  __syncthreads();
  if (wid == 0) {
    #pragma unroll
    for (int w = 1; w < 4; ++w) { mx = fmaxf(mx, smx[w][lane]); sm += ssm[w][lane]; }
    p[b * 2048 + c] = mx;
    p[b * 2048 + 1024 + c] = sm * (1.f / 2048.f);
  }
}

// ---------------- MLP layer kernels: one wave per output neuron ---------------
__global__ __launch_bounds__(256) void mlp1_k(const float* __restrict__ p,
                                              const float* __restrict__ w,
                                              const float* __restrict__ s10,
                                              const float* __restrict__ b10,
                                              float* __restrict__ h1) {
  int o = (blockIdx.x << 2) + (threadIdx.x >> 6);
  int lane = threadIdx.x & 63;
  const float4* wr = (const float4*)(w + (size_t)o * 2048);
  float acc[NB] = {};
  for (int i = lane; i < 512; i += 64) {
    float4 wv = wr[i];
    #pragma unroll
    for (int b = 0; b < NB; ++b) {
      float4 pv = ((const float4*)(p + b * 2048))[i];
      acc[b] += wv.x * pv.x + wv.y * pv.y + wv.z * pv.z + wv.w * pv.w;
    }
  }
  #pragma unroll
  for (int off = 32; off; off >>= 1)
    #pragma unroll
    for (int b = 0; b < NB; ++b) acc[b] += __shfl_xor(acc[b], off);
  if (lane == 0) {
    float sc = s10[o], bc = b10[o];
    #pragma unroll
    for (int b = 0; b < NB; ++b) h1[b * 512 + o] = lrelu(fmaf(acc[b], sc, bc));
  }
}

__global__ __launch_bounds__(256) void mlp2_k(const float* __restrict__ h1,
                                              const float* __restrict__ w,
                                              const float* __restrict__ l2b,
                                              const float* __restrict__ s11,
                                              const float* __restrict__ b11,
                                              float* __restrict__ h2) {
  int o = (blockIdx.x << 2) + (threadIdx.x >> 6);
  int lane = threadIdx.x & 63;
  const float4* wr = (const float4*)(w + (size_t)o * 512);
  float acc[NB] = {};
  for (int i = lane; i < 128; i += 64) {
    float4 wv = wr[i];
    #pragma unroll
    for (int b = 0; b < NB; ++b) {
      float4 pv = ((const float4*)(h1 + b * 512))[i];
      acc[b] += wv.x * pv.x + wv.y * pv.y + wv.z * pv.z + wv.w * pv.w;
    }
  }
  #pragma unroll
  for (int off = 32; off; off >>= 1)
    #pragma unroll
    for (int b = 0; b < NB; ++b) acc[b] += __shfl_xor(acc[b], off);
  if (lane == 0) {
    float bl = l2b[o], sc = s11[o], bc = b11[o];
    #pragma unroll
    for (int b = 0; b < NB; ++b) h2[b * 256 + o] = lrelu(fmaf(acc[b] + bl, sc, bc));
  }
}

__global__ __launch_bounds__(256) void mlp3_k(const float* __restrict__ h2,
                                              const float* __restrict__ w,
                                              const float* __restrict__ l3b,
                                              float* __restrict__ outp) {
  int o = (blockIdx.x << 2) + (threadIdx.x >> 6);
  int lane = threadIdx.x & 63;
  if (o >= 40) return;
  const float4* wr = (const float4*)(w + (size_t)o * 256);
  float acc[NB] = {};
  for (int i = lane; i < 64; i += 64) {
    float4 wv = wr[i];
    #pragma unroll
    for (int b = 0; b < NB; ++b) {
      float4 pv = ((const float4*)(h2 + b * 256))[i];
      acc[b] += wv.x * pv.x + wv.y * pv.y + wv.z * pv.z + wv.w * pv.w;
    }
  }
  #pragma unroll
  for (int off = 32; off; off >>= 1)
    #pragma unroll
    for (int b = 0; b < NB; ++b) acc[b] += __shfl_xor(acc[b], off);
  if (lane == 0) {
    float bl = l3b[o];
    #pragma unroll
    for (int b = 0; b < NB; ++b) outp[b * 40 + o] = acc[b] + bl;
  }
}

// ---------------- host orchestration ------------------------------------------
extern "C" void kernel_launch(void* const* d_in, const int* in_sizes, int n_in,
                              void* d_out, int out_size, void* d_ws, size_t ws_size,
                              hipStream_t stream) {
  const float* x = (const float*)d_in[0];
  const void* loc = d_in[1];
  const float* geod = (const float*)d_in[2];
  const float* w[9];
  for (int i = 0; i < 9; ++i) w[i] = (const float*)d_in[3 + i];
  const float* bn[11];
  for (int i = 0; i < 11; ++i) bn[i] = (const float*)d_in[12 + i];
  const float* l1w = (const float*)d_in[23];
  const float* l2w = (const float*)d_in[24];
  const float* l2b = (const float*)d_in[25];
  const float* l3w = (const float*)d_in[26];
  const float* l3b = (const float*)d_in[27];
  float* outp = (float*)d_out;

  char* base = (char*)d_ws;
  size_t off = 0;
  auto alloc = [&](size_t bytes) -> void* {
    void* p = base + off;
    off += (bytes + 255) & ~(size_t)255;
    return p;
  };
  int* mode = (int*)alloc(4);
  float* x0 = (float*)alloc((size_t)NROWS * 3 * 4);
  int* idxL = (int*)alloc((size_t)NROWS * 16 * 4);
  int* idxG = (int*)alloc((size_t)NROWS * 32 * 4);
  static const int Oc[9] = {64, 64, 128, 256, 64, 64, 128, 256, 1024};
  static const int Cc[9] = {3, 64, 64, 128, 3, 64, 64, 128, 512};
  float* wt[9];
  for (int l = 0; l < 9; ++l) {
    int n2 = (l == 8) ? Oc[l] : 2 * Oc[l];
    wt[l] = (float*)alloc((size_t)Cc[l] * n2 * 4);
  }
  static const int bc[11] = {64, 64, 128, 256, 64, 64, 128, 256, 1024, 512, 256};
  float *bns[11], *bnb[11];
  for (int i = 0; i < 11; ++i) {
    bns[i] = (float*)alloc((size_t)bc[i] * 4);
    bnb[i] = (float*)alloc((size_t)bc[i] * 4);
  }
  float* z = (float*)alloc((size_t)NROWS * 1024 * 4);      // reused: conv z / layer-9 y
  float* xcatL = (float*)alloc((size_t)NROWS * 512 * 4);
  float* xcatG = (float*)alloc((size_t)NROWS * 512 * 4);
  float* xm = (float*)alloc((size_t)NROWS * 512 * 4);
  float* pbuf = (float*)alloc((size_t)NB * 2048 * 4);
  float* h1 = (float*)alloc((size_t)NB * 512 * 4);
  float* h2 = (float*)alloc((size_t)NB * 256 * 4);

  detect_mode_k<<<1, 256, 0, stream>>>((const uint32_t*)loc, mode);

  PrepArgs pa;
  pa.x = x; pa.x0 = x0;
  for (int l = 0; l < 9; ++l) { pa.w[l] = w[l]; pa.wt[l] = wt[l]; pa.O[l] = Oc[l]; pa.C[l] = Cc[l]; }
  for (int i = 0; i < 11; ++i) { pa.bn[i] = bn[i]; pa.bns[i] = bns[i]; pa.bnb[i] = bnb[i]; pa.bc[i] = bc[i]; }
  int total = NROWS * 3;
  for (int l = 0; l < 9; ++l) total += Cc[l] * ((l == 8) ? Oc[l] : 2 * Oc[l]);
  for (int i = 0; i < 11; ++i) total += bc[i];
  prep_k<<<(total + 255) / 256, 256, 0, stream>>>(pa);

  knn_k<<<NROWS / 2, 256, 0, stream>>>(geod, loc, mode, idxL, idxG);  // 4 wave-tasks/block

  auto gemm = [&](const float* A, int lda, const float* Bt, int K, int N2, float* C, int ldc,
                  const float* sc, const float* bi, int act) {
    if (N2 >= 512) {
      dim3 grid(NROWS / GBM, N2 / GBN);
      gemmbig_k<<<grid, 256, 0, stream>>>(A, lda, Bt, K, N2, C, ldc, sc, bi, act);
    } else {
      dim3 grid(NROWS / BM, N2 / BNC);
      gemm_k<<<grid, 256, 0, stream>>>(A, lda, Bt, K, N2, C, ldc, sc, bi, act);
    }
  };
  auto gather = [&](int K, int O, const int* idx, const float* sc, const float* bi, float* op) {
    dim3 grid(NROWS / 4);
    if (K == 16) {
      if (O == 64)       gather_k<16, 64><<<grid, 256, 0, stream>>>(z, idx, sc, bi, op);
      else if (O == 128) gather_k<16, 128><<<grid, 256, 0, stream>>>(z, idx, sc, bi, op);
      else               gather_k<16, 256><<<grid, 256, 0, stream>>>(z, idx, sc, bi, op);
    } else {
      if (O == 64)       gather_k<32, 64><<<grid, 256, 0, stream>>>(z, idx, sc, bi, op);
      else if (O == 128) gather_k<32, 128><<<grid, 256, 0, stream>>>(z, idx, sc, bi, op);
      else               gather_k<32, 256><<<grid, 256, 0, stream>>>(z, idx, sc, bi, op);
    }
  };

  static const int coff[4] = {0, 64, 128, 256};
  for (int l = 0; l < 4; ++l) {   // local chain (K=16, w1-4, bn1-4)
    const float* A = (l == 0) ? x0 : (xcatL + coff[l - 1]);
    int lda = (l == 0) ? 3 : 512;
    gemm(A, lda, wt[l], Cc[l], 2 * Oc[l], z, 2 * Oc[l], nullptr, nullptr, 0);
    gather(16, Oc[l], idxL, bns[l], bnb[l], xcatL + coff[l]);
  }
  for (int l = 0; l < 4; ++l) {   // global chain (K=32, w5-8, bn5-8)
    const float* A = (l == 0) ? x0 : (xcatG + coff[l - 1]);
    int lda = (l == 0) ? 3 : 512;
    gemm(A, lda, wt[4 + l], Cc[4 + l], 2 * Oc[4 + l], z, 2 * Oc[4 + l], nullptr, nullptr, 0);
    gather(32, Oc[4 + l], idxG, bns[4 + l], bnb[4 + l], xcatG + coff[l]);
  }

  select_k<<<(NROWS * 512 / 4) / 256, 256, 0, stream>>>(xcatL, xcatG, loc, mode, xm);
  gemm(xm, 512, wt[8], 512, 1024, z, 1024, bns[8], bnb[8], 1);   // layer 9 + BN9 + leaky fused
  reduce_np_k<<<NB * 16, 256, 0, stream>>>(z, pbuf);
  mlp1_k<<<128, 256, 0, stream>>>(pbuf, l1w, bns[9], bnb[9], h1);
  mlp2_k<<<64, 256, 0, stream>>>(h1, l2w, l2b, bns[10], bnb[10], h2);
  mlp3_k<<<10, 256, 0, stream>>>(h2, l3w, l3b, outp);
}